// Round 1
// baseline (1863.914 us; speedup 1.0000x reference)
//
#include <hip/hip_runtime.h>
#include <hip/hip_bf16.h>

#define D_DIM 128
#define KT 128
#define JF 64
#define WB_BLOCKS 256
// 64 nodes per bucket; NB = ceil(nNodes/64). Scan kernel supports NB <= 2048
// (nNodes <= 131072; problem has 100000 -> NB = 1563).
#define BUCKET_SHIFT 6

typedef __attribute__((ext_vector_type(8))) short bf16x8;
typedef __attribute__((ext_vector_type(4))) float f32x4;

__device__ inline unsigned short f2b(float f) {
    __hip_bfloat16 h = __float2bfloat16(f);
    return *reinterpret_cast<unsigned short*>(&h);
}
__device__ inline float b2f(unsigned short u) {
    unsigned int x = ((unsigned int)u) << 16;
    return __uint_as_float(x);
}

// ---------------------------------------------------------------------------
// Edge phase, v2: bucket-sort edge IDs by i>>6, then owner-computes gather.
// Replaces the atomic-scatter edge_pass (314 MB write-through atomic traffic
// at ~0.83 TB/s) with plain streaming loads + exclusive LDS accumulation.
// ---------------------------------------------------------------------------

// hist: bucket histogram of edge_i>>6 (LDS-privatized)
__global__ void __launch_bounds__(1024) hist_kernel(
    const int* __restrict__ edge_i, unsigned* __restrict__ bcnt, int E, int NB)
{
    __shared__ unsigned h[2048];
    for (int t = threadIdx.x; t < 2048; t += 1024) h[t] = 0u;
    __syncthreads();
    int stride = gridDim.x * 1024;
    for (int e = blockIdx.x * 1024 + threadIdx.x; e < E; e += stride)
        atomicAdd(&h[edge_i[e] >> BUCKET_SHIFT], 1u);
    __syncthreads();
    for (int t = threadIdx.x; t < NB; t += 1024)
        if (h[t]) atomicAdd(&bcnt[t], h[t]);
}

// scan: single-block exclusive prefix over NB (<=2048) bucket counts.
// Writes base[] (for gather) and ptr[] (running cursors for scatter,
// padded to 64B stride to avoid false sharing on hot atomics).
__global__ void __launch_bounds__(1024) scan_kernel(
    const unsigned* __restrict__ bcnt, unsigned* __restrict__ base,
    unsigned* __restrict__ ptr, int NB, int E)
{
    __shared__ unsigned s[2048];
    __shared__ unsigned segoff[64];
    int t = threadIdx.x;
    s[t]        = (t        < NB) ? bcnt[t]        : 0u;
    s[t + 1024] = (t + 1024 < NB) ? bcnt[t + 1024] : 0u;
    __syncthreads();
    if (t < 64) {
        unsigned acc = 0;
        #pragma unroll
        for (int j = 0; j < 32; ++j) {        // exclusive scan within 32-seg
            unsigned v = s[t * 32 + j];
            s[t * 32 + j] = acc;
            acc += v;
        }
        unsigned x = acc;                     // inclusive scan of segment sums
        #pragma unroll
        for (int off = 1; off < 64; off <<= 1) {
            unsigned y = __shfl_up(x, off, 64);
            if (t >= off) x += y;
        }
        segoff[t] = x - acc;                  // exclusive segment offset
    }
    __syncthreads();
    for (int idx = t; idx < NB; idx += 1024) {
        unsigned o = s[idx] + segoff[idx >> 5];
        base[idx] = o;
        ptr[idx * 16] = o;
    }
    if (t == 0) base[NB] = (unsigned)E;
}

// scatter: write packed (edge_id, i_low6 | k<<8) to the bucket region.
// Also cntw (per-k edge count), LDS-privatized.
__global__ void __launch_bounds__(256) scatter_kernel(
    const int* __restrict__ edge_i, const int* __restrict__ edge_k,
    unsigned* __restrict__ ptr, uint2* __restrict__ sorted,
    unsigned* __restrict__ cntw, int E)
{
    __shared__ unsigned cw[128];
    if (threadIdx.x < 128) cw[threadIdx.x] = 0u;
    __syncthreads();
    int stride = gridDim.x * 256;
    for (int e = blockIdx.x * 256 + threadIdx.x; e < E; e += stride) {
        int i = edge_i[e], k = edge_k[e];
        unsigned pos = atomicAdd(&ptr[(i >> BUCKET_SHIFT) * 16], 1u);
        uint2 p;
        p.x = (unsigned)e;
        p.y = (unsigned)((i & 63) | (k << 8));
        sorted[pos] = p;
        atomicAdd(&cw[k], 1u);
    }
    __syncthreads();
    if (threadIdx.x < 128 && cw[threadIdx.x])
        atomicAdd(&cntw[threadIdx.x], cw[threadIdx.x]);
}

// gather: block owns buckets (64 nodes each) exclusively.
// Accumulates Xi (f32), Nmat (packed u8x4 in u32) in LDS; plain stores out.
// Xk/cntraw/invcnt also produced here. Per-edge cost: one coalesced 256B
// read of edge_x + 2 LDS float atomics per lane (fire-and-forget).
__global__ void __launch_bounds__(512) gather_kernel(
    const float* __restrict__ edge_x, const uint2* __restrict__ sorted,
    const unsigned* __restrict__ base, float* __restrict__ Xi,
    float* __restrict__ Xk, unsigned char* __restrict__ Nmat8,
    float* __restrict__ cntraw, float* __restrict__ invcnt, int nNodes, int NB)
{
    __shared__ float    xi_s[64 * 64];    // 16 KB  [node_lo][d]
    __shared__ unsigned nm_s[64 * 32];    //  8 KB  [node_lo][k>>2] packed u8x4
    __shared__ float    xk_s[128 * 64];   // 32 KB  [k][d] (persists over buckets)
    __shared__ uint2    pk_s[512];        //  4 KB  staged packed entries
    const int tid = threadIdx.x;
    const int wid = tid >> 6, lane = tid & 63;

    for (int t = tid; t < 128 * 64; t += 512) xk_s[t] = 0.f;

    for (int b = blockIdx.x; b < NB; b += gridDim.x) {
        for (int t = tid; t < 64 * 64; t += 512) xi_s[t] = 0.f;
        for (int t = tid; t < 64 * 32; t += 512) nm_s[t] = 0u;
        __syncthreads();
        const unsigned s0 = base[b], s1 = base[b + 1];
        for (unsigned c = s0; c < s1; c += 512) {
            const int n = (int)min(512u, s1 - c);
            if (tid < n) pk_s[tid] = sorted[c + tid];
            __syncthreads();
            #pragma unroll 4
            for (int j = wid; j < n; j += 8) {
                uint2 p = pk_s[j];
                int id = (int)p.x;
                int il = (int)(p.y & 63u);
                int k  = (int)((p.y >> 8) & 127u);
                float x = edge_x[(long)id * 64 + lane];
                atomicAdd(&xi_s[il * 64 + lane], x);
                atomicAdd(&xk_s[k * 64 + lane], x);
                if (lane == 0) atomicAdd(&nm_s[il * 32 + (k >> 2)], 1u << ((k & 3) * 8));
            }
            __syncthreads();
        }
        // flush bucket (exclusive ownership -> plain coalesced stores)
        const int nodeBase = b << BUCKET_SHIFT;
        for (int t = tid; t < 64 * 64; t += 512) {
            int nd = nodeBase + (t >> 6);
            if (nd < nNodes) Xi[(long)nd * 64 + (t & 63)] = xi_s[t];
        }
        for (int t = tid; t < 64 * 32; t += 512) {
            int nd = nodeBase + (t >> 5);
            if (nd < nNodes) {
                unsigned wv = nm_s[t];
                uchar4 o;
                o.x = (unsigned char)(wv & 0xFF);
                o.y = (unsigned char)((wv >> 8) & 0xFF);
                o.z = (unsigned char)((wv >> 16) & 0xFF);
                o.w = (unsigned char)(wv >> 24);
                *(uchar4*)&Nmat8[(long)nd * 128 + (t & 31) * 4] = o;
            }
        }
        {   // per-node count: 8 lanes/node, each sums 4 packed words
            int g = tid >> 3, sub = tid & 7;
            int nd = nodeBase + g;
            unsigned ssum = 0;
            #pragma unroll
            for (int q = 0; q < 4; ++q) {
                unsigned wv = nm_s[g * 32 + sub * 4 + q];
                ssum += (wv & 0xFF) + ((wv >> 8) & 0xFF) + ((wv >> 16) & 0xFF) + (wv >> 24);
            }
            #pragma unroll
            for (int o = 4; o; o >>= 1) ssum += __shfl_down(ssum, o, 8);
            if (sub == 0 && nd < nNodes) {
                float cf = (float)ssum;
                cntraw[nd] = cf;
                invcnt[nd] = 1.f / fmaxf(cf, 1.f);
            }
        }
        __syncthreads();
    }
    for (int t = tid; t < 128 * 64; t += 512) {
        float v = xk_s[t];
        if (v != 0.f) unsafeAtomicAdd(&Xk[t], v);
    }
}

// u0cvt: fp32 -> bf16 (identical rounding to the staging that consumed fp32 before)
__global__ void __launch_bounds__(256) u0cvt_kernel(
    const float* __restrict__ in, unsigned short* __restrict__ out, long n4)
{
    long i = (long)blockIdx.x * 256 + threadIdx.x;
    long stride = (long)gridDim.x * 256;
    for (; i < n4; i += stride) {
        float4 v = *(const float4*)&in[i * 4];
        ushort4 o = make_ushort4(f2b(v.x), f2b(v.y), f2b(v.z), f2b(v.w));
        *(ushort4*)&out[i * 4] = o;
    }
}

// ---------------------------------------------------------------------------
// prep: fused P2/P3/ebx/btprep. Bt[n][kk] (bf16, stride 320)
// ---------------------------------------------------------------------------
__global__ void prep_kernel(const float* __restrict__ uWt, const float* __restrict__ Wl,
                            const float* __restrict__ uWb, const float* __restrict__ ep_W,
                            const float* __restrict__ ep_b,
                            unsigned short* __restrict__ Bt, float* __restrict__ ebx)
{
    int idx = blockIdx.x * 256 + threadIdx.x;
    if (idx < 128 * 320) {
        int n = idx / 320, kk = idx - n * 320;
        float v;
        if (kk < 128) {
            v = uWt[kk * 128 + n];
        } else {
            const float* a = (kk < 256) ? (Wl + (kk - 128) * 128) : (ep_W + (kk - 256) * 128);
            float s = 0.f;
            #pragma unroll 8
            for (int j = 0; j < 128; ++j) s += a[j] * uWb[j * 128 + n];
            v = s;
        }
        Bt[idx] = f2b(v);
    } else if (idx < 128 * 320 + 128) {
        int n = idx - 128 * 320;
        float s = 0.f;
        #pragma unroll 8
        for (int j = 0; j < 128; ++j) s += ep_b[j] * uWb[j * 128 + n];
        ebx[n] = s;
    }
}

// ---------------------------------------------------------------------------
// layerA MFMA: U_out(bf16) = relu(A[128x320]@B[320x128] + ub + flag*ebx)
// A = [U(bf16) | N*inv | Xi*inv]
// ---------------------------------------------------------------------------
__global__ void __launch_bounds__(256) layerA_mfma(
    const unsigned short* __restrict__ U_in, const unsigned char* __restrict__ Nmat8,
    const float* __restrict__ Xi, const float* __restrict__ cntraw,
    const float* __restrict__ invcnt, const unsigned short* __restrict__ Bt,
    const float* __restrict__ ub_l, const float* __restrict__ ebx,
    unsigned short* __restrict__ U_out, int nNodes)
{
    __shared__ __align__(16) unsigned short A_s[128][40];
    __shared__ __align__(16) unsigned short B_s[128][40];
    const int tid = threadIdx.x;
    const int w = tid >> 6, lane = tid & 63;
    const int quad = lane >> 4, l16 = lane & 15;
    const int nodeBase = blockIdx.x * 128;
    f32x4 acc[2][8];
    #pragma unroll
    for (int a = 0; a < 2; ++a)
        #pragma unroll
        for (int b = 0; b < 8; ++b) acc[a][b] = (f32x4){0.f, 0.f, 0.f, 0.f};

    const int rr = tid >> 3;          // 0..31
    const int kc = (tid & 7) * 4;     // 0..28

    for (int ks = 0; ks < 10; ++ks) {
        const int k0 = ks * 32;
        __syncthreads();
        {
            int n = tid & 127, seg = tid >> 7;
            const unsigned short* src = Bt + n * 320 + k0 + seg * 16;
            uint4 p0 = *(const uint4*)(src);
            uint4 p1 = *(const uint4*)(src + 8);
            *(uint4*)&B_s[n][seg * 16]     = p0;
            *(uint4*)&B_s[n][seg * 16 + 8] = p1;
        }
        #pragma unroll
        for (int p = 0; p < 4; ++p) {
            int r = p * 32 + rr;
            int node = nodeBase + r;
            ushort4 w4 = make_ushort4(0, 0, 0, 0);
            if (node < nNodes) {
                if (ks < 4) {
                    w4 = *(const ushort4*)&U_in[(long)node * 128 + k0 + kc];
                } else if (ks < 8) {
                    float inv = invcnt[node];
                    const unsigned char* np_ = &Nmat8[(long)node * 128 + (k0 - 128) + kc];
                    w4 = make_ushort4(f2b((float)np_[0] * inv), f2b((float)np_[1] * inv),
                                      f2b((float)np_[2] * inv), f2b((float)np_[3] * inv));
                } else {
                    float inv = invcnt[node];
                    float4 x = *(const float4*)&Xi[(long)node * 64 + (k0 - 256) + kc];
                    w4 = make_ushort4(f2b(x.x * inv), f2b(x.y * inv),
                                      f2b(x.z * inv), f2b(x.w * inv));
                }
            }
            *(ushort4*)&A_s[r][kc] = w4;
        }
        __syncthreads();
        bf16x8 a0 = *(const bf16x8*)&A_s[w * 32 + l16][quad * 8];
        bf16x8 a1 = *(const bf16x8*)&A_s[w * 32 + 16 + l16][quad * 8];
        #pragma unroll
        for (int nt = 0; nt < 8; ++nt) {
            bf16x8 b = *(const bf16x8*)&B_s[nt * 16 + l16][quad * 8];
            acc[0][nt] = __builtin_amdgcn_mfma_f32_16x16x32_bf16(a0, b, acc[0][nt], 0, 0, 0);
            acc[1][nt] = __builtin_amdgcn_mfma_f32_16x16x32_bf16(a1, b, acc[1][nt], 0, 0, 0);
        }
    }
    #pragma unroll
    for (int mt = 0; mt < 2; ++mt) {
        #pragma unroll
        for (int r = 0; r < 4; ++r) {
            int row = w * 32 + mt * 16 + quad * 4 + r;
            int node = nodeBase + row;
            if (node < nNodes) {
                float flag = (cntraw[node] > 0.f) ? 1.f : 0.f;
                #pragma unroll
                for (int nt = 0; nt < 8; ++nt) {
                    int col = nt * 16 + l16;
                    float vv = acc[mt][nt][r] + ub_l[col] + flag * ebx[col];
                    U_out[(long)node * 128 + col] = f2b(fmaxf(vv, 0.f));
                }
            }
        }
    }
}

// ---------------------------------------------------------------------------
// wmsgB MFMA: partial[b] = N^T_chunk @ U_chunk  (U already bf16)
// ---------------------------------------------------------------------------
__global__ void __launch_bounds__(256) wmsgB_mfma(
    const unsigned short* __restrict__ U, const unsigned char* __restrict__ Nmat8,
    float* __restrict__ partial, int nodes_per_block, int nNodes)
{
    __shared__ __align__(16) unsigned short A_s[128][40];  // [ktok][node]
    __shared__ __align__(16) unsigned short B_s[128][40];  // [d][node]
    const int tid = threadIdx.x;
    const int w = tid >> 6, lane = tid & 63;
    const int quad = lane >> 4, l16 = lane & 15;
    f32x4 acc[2][8];
    #pragma unroll
    for (int a = 0; a < 2; ++a)
        #pragma unroll
        for (int b = 0; b < 8; ++b) acc[a][b] = (f32x4){0.f, 0.f, 0.f, 0.f};

    int base = blockIdx.x * nodes_per_block;
    int end = min(base + nodes_per_block, nNodes);
    const int nn = tid >> 3;          // 0..31
    const int cc = (tid & 7) * 16;    // 0..112
    for (int g = base; g < end; g += 32) {
        int cnt = min(32, end - g);
        __syncthreads();
        if (nn < cnt) {
            int node = g + nn;
            uint4 nb = *(const uint4*)&Nmat8[(long)node * 128 + cc];
            const unsigned char* nbp = (const unsigned char*)&nb;
            uint4 ua = *(const uint4*)&U[(long)node * 128 + cc];
            uint4 ubb = *(const uint4*)&U[(long)node * 128 + cc + 8];
            unsigned short uv[16];
            *(uint4*)&uv[0] = ua;
            *(uint4*)&uv[8] = ubb;
            #pragma unroll
            for (int j = 0; j < 16; ++j) {
                A_s[cc + j][nn] = f2b((float)nbp[j]);
                B_s[cc + j][nn] = uv[j];
            }
        } else {
            #pragma unroll
            for (int j = 0; j < 16; ++j) { A_s[cc + j][nn] = 0; B_s[cc + j][nn] = 0; }
        }
        __syncthreads();
        bf16x8 a0 = *(const bf16x8*)&A_s[w * 32 + l16][quad * 8];
        bf16x8 a1 = *(const bf16x8*)&A_s[w * 32 + 16 + l16][quad * 8];
        #pragma unroll
        for (int nt = 0; nt < 8; ++nt) {
            bf16x8 b = *(const bf16x8*)&B_s[nt * 16 + l16][quad * 8];
            acc[0][nt] = __builtin_amdgcn_mfma_f32_16x16x32_bf16(a0, b, acc[0][nt], 0, 0, 0);
            acc[1][nt] = __builtin_amdgcn_mfma_f32_16x16x32_bf16(a1, b, acc[1][nt], 0, 0, 0);
        }
    }
    float* my = partial + (size_t)blockIdx.x * 16384;
    #pragma unroll
    for (int mt = 0; mt < 2; ++mt)
        #pragma unroll
        for (int r = 0; r < 4; ++r) {
            int row = w * 32 + mt * 16 + quad * 4 + r;
            #pragma unroll
            for (int nt = 0; nt < 8; ++nt)
                my[row * 128 + nt * 16 + l16] = acc[mt][nt][r];
        }
}

// reduceP: 512 blocks = 64 idx-tiles x 8 partial-groups of 32; atomic flush
// into Wmsg (zeroed by the up-front memset).
__global__ void __launch_bounds__(256) reduceP_kernel(
    const float* __restrict__ partial, float* __restrict__ Wmsg)
{
    int grp = blockIdx.x >> 6;          // 0..7
    int ib  = blockIdx.x & 63;          // 0..63
    int idx = ib * 256 + threadIdx.x;   // 0..16383
    float s = 0.f;
    #pragma unroll 8
    for (int b = 0; b < 32; ++b)
        s += partial[(size_t)(grp * 32 + b) * 16384 + idx];
    unsafeAtomicAdd(&Wmsg[idx], s);
}

__global__ void wmsg_fin_kernel(const float* __restrict__ Wmsg, const float* __restrict__ Xk,
                                const unsigned* __restrict__ cntw, const float* __restrict__ ep_W,
                                const float* __restrict__ ep_b, float* __restrict__ out)
{
    int idx = blockIdx.x * 256 + threadIdx.x;
    int kk = idx >> 7, d = idx & 127;
    float s = Wmsg[idx];
    const float* xk = Xk + kk * 64;
    #pragma unroll 8
    for (int j = 0; j < 64; ++j) s += xk[j] * ep_W[j * 128 + d];
    float c = (float)cntw[kk];
    s += c * ep_b[d];
    out[idx] = s / fmaxf(c, 1.f);
}

__global__ void gemm_kernel(const float* __restrict__ A, const float* __restrict__ B,
                            const float* __restrict__ A2, const float* __restrict__ B2,
                            const float* __restrict__ bias, const float* __restrict__ res,
                            float* __restrict__ C, int M, int N, int K, int K2, int act)
{
    int idx = blockIdx.x * 256 + threadIdx.x;
    if (idx >= M * N) return;
    int m = idx / N, n = idx - m * N;
    float s = bias ? bias[n] : 0.f;
    const float* a = A + (long)m * K;
    for (int k = 0; k < K; ++k) s += a[k] * B[(long)k * N + n];
    if (A2) {
        const float* a2 = A2 + (long)m * K2;
        for (int k = 0; k < K2; ++k) s += a2[k] * B2[(long)k * N + n];
    }
    if (res) s += res[idx];
    if (act) s = fmaxf(s, 0.f);
    C[idx] = s;
}

__global__ void add_kernel(const float* __restrict__ A, const float* __restrict__ B,
                           float* __restrict__ C, int n)
{
    int i = blockIdx.x * 256 + threadIdx.x;
    if (i < n) C[i] = A[i] + B[i];
}

// fused Q/K/V projection: 128 tokens x 384 outputs
__global__ void qkv_kernel(const float* __restrict__ X,
                           const float* __restrict__ Wq, const float* __restrict__ Wk,
                           const float* __restrict__ Wv, const float* __restrict__ bq,
                           const float* __restrict__ bk, const float* __restrict__ bv,
                           float* __restrict__ qm, float* __restrict__ km, float* __restrict__ vm)
{
    int idx = blockIdx.x * 256 + threadIdx.x;
    if (idx >= 128 * 384) return;
    int m = idx / 384, c = idx - m * 384;
    int sel = c >> 7, n = c & 127;
    const float* W = (sel == 0) ? Wq : (sel == 1) ? Wk : Wv;
    const float* b = (sel == 0) ? bq : (sel == 1) ? bk : bv;
    float s = b[n];
    const float* x = X + m * 128;
    #pragma unroll 8
    for (int k = 0; k < 128; ++k) s += x[k] * W[k * 128 + n];
    float* o = (sel == 0) ? qm : (sel == 1) ? km : vm;
    o[m * 128 + n] = s;
}

__global__ void attn_kernel(const float* __restrict__ q, const float* __restrict__ kmat,
                            const float* __restrict__ vmat, float* __restrict__ outp)
{
    __shared__ float p_s[128];
    __shared__ float red_s[4];
    const int tok = blockIdx.x;
    const int t = threadIdx.x;
    const int lane = t & 63, wid = t >> 6;
    for (int h = 0; h < 2; ++h) {
        const float* qr = q + tok * 128 + h * 64;
        const float* kr = kmat + t * 128 + h * 64;
        float s = 0.f;
        #pragma unroll
        for (int d = 0; d < 64; ++d) s += qr[d] * kr[d];
        s *= 0.125f;
        float m = s;
        #pragma unroll
        for (int o = 32; o; o >>= 1) m = fmaxf(m, __shfl_down(m, o, 64));
        if (lane == 0) red_s[wid] = m;
        __syncthreads();
        m = fmaxf(red_s[0], red_s[1]);
        float ev = expf(s - m);
        float ss = ev;
        #pragma unroll
        for (int o = 32; o; o >>= 1) ss += __shfl_down(ss, o, 64);
        if (lane == 0) red_s[2 + wid] = ss;
        __syncthreads();
        float tot = red_s[2] + red_s[3];
        p_s[t] = ev / tot;
        __syncthreads();
        if (t < 64) {
            float o = 0.f;
            #pragma unroll 8
            for (int j = 0; j < 128; ++j) o += p_s[j] * vmat[j * 128 + h * 64 + t];
            outp[tok * 128 + h * 64 + t] = o;
        }
        __syncthreads();
    }
}

__global__ void ln_kernel(const float* __restrict__ x, const float* __restrict__ g,
                          const float* __restrict__ b, float* __restrict__ y)
{
    __shared__ float red_s[4];
    const int row = blockIdx.x, t = threadIdx.x, lane = t & 63, wid = t >> 6;
    float v = x[row * 128 + t];
    float s = v;
    #pragma unroll
    for (int o = 32; o; o >>= 1) s += __shfl_down(s, o, 64);
    if (lane == 0) red_s[wid] = s;
    __syncthreads();
    float mean = (red_s[0] + red_s[1]) * (1.f / 128.f);
    float d = v - mean;
    float q2 = d * d;
    #pragma unroll
    for (int o = 32; o; o >>= 1) q2 += __shfl_down(q2, o, 64);
    if (lane == 0) red_s[2 + wid] = q2;
    __syncthreads();
    float var = (red_s[2] + red_s[3]) * (1.f / 128.f);
    y[row * 128 + t] = d * rsqrtf(var + 1e-5f) * g[t] + b[t];
}

// decode: 16 lanes per triple; U2 bf16 rows (16B/lane), Wf/V fp32
__global__ void __launch_bounds__(256) decode_kernel(
    const int* __restrict__ idx_i, const int* __restrict__ idx_j, const int* __restrict__ idx_k,
    const unsigned short* __restrict__ U2, const float* __restrict__ Wf, const float* __restrict__ V,
    const float* __restrict__ bias, float* __restrict__ out, int n)
{
    const int g = threadIdx.x >> 4;      // 0..15
    const int hl = threadIdx.x & 15;
    int t = blockIdx.x * 16 + g;
    if (t >= n) return;
    int i = idx_i[t], j = idx_j[t], kk = idx_k[t];
    const unsigned short* up = U2 + (long)i * 128 + hl * 8;
    const float* wp = Wf + kk * 128 + hl * 8;
    const float* vp = V + j * 128 + hl * 8;
    uint4 ur = *(const uint4*)up;                 // 8 bf16
    const unsigned short* uu = (const unsigned short*)&ur;
    float4 w0 = *(const float4*)wp,  w1 = *(const float4*)(wp + 4);
    float4 v0 = *(const float4*)vp,  v1 = *(const float4*)(vp + 4);
    float s = b2f(uu[0]) * w0.x * v0.x + b2f(uu[1]) * w0.y * v0.y
            + b2f(uu[2]) * w0.z * v0.z + b2f(uu[3]) * w0.w * v0.w
            + b2f(uu[4]) * w1.x * v1.x + b2f(uu[5]) * w1.y * v1.y
            + b2f(uu[6]) * w1.z * v1.z + b2f(uu[7]) * w1.w * v1.w;
    #pragma unroll
    for (int o = 8; o; o >>= 1) s += __shfl_down(s, o, 16);
    if (hl == 0) out[t] = 1.f / (1.f + expf(-(s + bias[0])));
}

// ---------------------------------------------------------------------------
extern "C" void kernel_launch(void* const* d_in, const int* in_sizes, int n_in,
                              void* d_out, int out_size, void* d_ws, size_t ws_size,
                              hipStream_t stream)
{
    const float* edge_x = (const float*)d_in[0];
    const int*   edge_i = (const int*)d_in[1];
    const int*   edge_k = (const int*)d_in[2];
    const int*   idx_i  = (const int*)d_in[3];
    const int*   idx_j  = (const int*)d_in[4];
    const int*   idx_k  = (const int*)d_in[5];
    const float* u0   = (const float*)d_in[6];
    const float* w0   = (const float*)d_in[7];
    const float* ep_W = (const float*)d_in[8];
    const float* ep_b = (const float*)d_in[9];
    const float* uW   = (const float*)d_in[10];
    const float* ub   = (const float*)d_in[11];
    const float* wW   = (const float*)d_in[12];
    const float* wb   = (const float*)d_in[13];
    const float* pos  = (const float*)d_in[14];
    const float* Wq = (const float*)d_in[15];
    const float* Wk = (const float*)d_in[16];
    const float* Wv = (const float*)d_in[17];
    const float* bq = (const float*)d_in[18];
    const float* bk = (const float*)d_in[19];
    const float* bv = (const float*)d_in[20];
    const float* Wo = (const float*)d_in[21];
    const float* bo = (const float*)d_in[22];
    const float* ln1_g = (const float*)d_in[23];
    const float* ln1_b = (const float*)d_in[24];
    const float* f_W1 = (const float*)d_in[25];
    const float* f_b1 = (const float*)d_in[26];
    const float* f_W2 = (const float*)d_in[27];
    const float* f_b2 = (const float*)d_in[28];
    const float* ln2_g = (const float*)d_in[29];
    const float* ln2_b = (const float*)d_in[30];
    const float* Vmat = (const float*)d_in[31];
    const float* bias = (const float*)d_in[32];

    const int E   = in_sizes[1];
    const int NTt = in_sizes[3];
    const int nNodes = in_sizes[6] / D_DIM;
    const int NB = (nNodes + 63) >> BUCKET_SHIFT;   // 64 nodes per bucket

    char* ws = (char*)d_ws;
    size_t off = 0;
    auto alloc = [&](size_t bytes) -> char* {
        char* p = ws + off;
        off = (off + bytes + 255) & ~(size_t)255;
        return p;
    };
    // zero-initialized region first (single small memset)
    unsigned* bcnt   = (unsigned*)alloc(2048 * 4);
    float*    Xkseg  = (float*)alloc(128 * 64 * 4);
    unsigned* cntw   = (unsigned*)alloc(512);
    float*    Wmsg0  = (float*)alloc(65536);
    float*    Wmsg1  = (float*)alloc(65536);
    size_t zeroBytes = off;
    // rest (written before read)
    unsigned* baseArr = (unsigned*)alloc(2049 * 4);
    unsigned* ptrArr  = (unsigned*)alloc(2048 * 16 * 4);     // 64B-strided cursors
    uint2*    sorted  = (uint2*)alloc((size_t)E * 8);
    float*    Xi      = (float*)alloc((size_t)nNodes * 64 * 4);
    unsigned char* Nmat8 = (unsigned char*)alloc((size_t)nNodes * 128);
    float* cntraw = (float*)alloc((size_t)nNodes * 4);
    float* invcnt = (float*)alloc((size_t)nNodes * 4);
    unsigned short* U0b = (unsigned short*)alloc((size_t)nNodes * 128 * 2);
    unsigned short* U1b = (unsigned short*)alloc((size_t)nNodes * 128 * 2);
    unsigned short* U2b = (unsigned short*)alloc((size_t)nNodes * 128 * 2);
    float* partials = (float*)alloc((size_t)WB_BLOCKS * 16384 * 4);
    unsigned short* Bt0 = (unsigned short*)alloc(128 * 320 * 2);
    unsigned short* Bt1 = (unsigned short*)alloc(128 * 320 * 2);
    float* W1 = (float*)alloc(65536);
    float* W2 = (float*)alloc(65536);
    float* ebx0 = (float*)alloc(512);
    float* ebx1 = (float*)alloc(512);
    float* Wmsgn0 = (float*)alloc(65536);
    float* Wmsgn1 = (float*)alloc(65536);
    float* Xmat  = (float*)alloc(65536);
    float* qm    = (float*)alloc(65536);
    float* km    = (float*)alloc(65536);
    float* vm    = (float*)alloc(65536);
    float* attnO = (float*)alloc(65536);
    float* pre1  = (float*)alloc(65536);
    float* H1m   = (float*)alloc(65536);
    float* F1    = (float*)alloc(262144);
    float* pre2  = (float*)alloc(65536);
    float* Wfm   = (float*)alloc(65536);

    const float* uWt0 = uW;
    const float* uWb0 = uW + 128 * 128;
    const float* uWt1 = uW + 256 * 128;
    const float* uWb1 = uW + 256 * 128 + 128 * 128;
    const float* wWt0 = wW;
    const float* wWb0 = wW + 128 * 128;
    const float* wWt1 = wW + 256 * 128;
    const float* wWb1 = wW + 256 * 128 + 128 * 128;

    hipMemsetAsync(d_ws, 0, zeroBytes, stream);

    // ---- edge phase: hist -> scan -> scatter -> gather ----
    hist_kernel<<<128, 1024, 0, stream>>>(edge_i, bcnt, E, NB);
    scan_kernel<<<1, 1024, 0, stream>>>(bcnt, baseArr, ptrArr, NB, E);
    scatter_kernel<<<1024, 256, 0, stream>>>(edge_i, edge_k, ptrArr, sorted, cntw, E);
    gather_kernel<<<512, 512, 0, stream>>>(edge_x, sorted, baseArr, Xi, Xkseg,
                                           Nmat8, cntraw, invcnt, nNodes, NB);
    u0cvt_kernel<<<1024, 256, 0, stream>>>(u0, U0b, (long)nNodes * 32);

    int npb = (nNodes + WB_BLOCKS - 1) / WB_BLOCKS;
    int la_grid = (nNodes + 127) / 128;

    // ---- layer 0 ----
    prep_kernel<<<161, 256, 0, stream>>>(uWt0, w0, uWb0, ep_W, ep_b, Bt0, ebx0);
    wmsgB_mfma<<<WB_BLOCKS, 256, 0, stream>>>(U0b, Nmat8, partials, npb, nNodes);
    reduceP_kernel<<<512, 256, 0, stream>>>(partials, Wmsg0);
    layerA_mfma<<<la_grid, 256, 0, stream>>>(U0b, Nmat8, Xi, cntraw, invcnt, Bt0, ub, ebx0, U1b, nNodes);
    wmsg_fin_kernel<<<64, 256, 0, stream>>>(Wmsg0, Xkseg, cntw, ep_W, ep_b, Wmsgn0);
    gemm_kernel<<<64, 256, 0, stream>>>(w0, wWt0, Wmsgn0, wWb0, wb, nullptr, W1, 128, 128, 128, 128, 1);

    // ---- layer 1 ----
    prep_kernel<<<161, 256, 0, stream>>>(uWt1, W1, uWb1, ep_W, ep_b, Bt1, ebx1);
    wmsgB_mfma<<<WB_BLOCKS, 256, 0, stream>>>(U1b, Nmat8, partials, npb, nNodes);
    reduceP_kernel<<<512, 256, 0, stream>>>(partials, Wmsg1);
    layerA_mfma<<<la_grid, 256, 0, stream>>>(U1b, Nmat8, Xi, cntraw, invcnt, Bt1, ub + 128, ebx1, U2b, nNodes);
    wmsg_fin_kernel<<<64, 256, 0, stream>>>(Wmsg1, Xkseg, cntw, ep_W, ep_b, Wmsgn1);
    gemm_kernel<<<64, 256, 0, stream>>>(W1, wWt1, Wmsgn1, wWb1, wb + 128, nullptr, W2, 128, 128, 128, 128, 1);

    // ---- TimeRefine ----
    add_kernel<<<64, 256, 0, stream>>>(W2, pos, Xmat, 128 * 128);
    qkv_kernel<<<192, 256, 0, stream>>>(Xmat, Wq, Wk, Wv, bq, bk, bv, qm, km, vm);
    attn_kernel<<<128, 128, 0, stream>>>(qm, km, vm, attnO);
    gemm_kernel<<<64, 256, 0, stream>>>(attnO, Wo, nullptr, nullptr, bo, Xmat, pre1, 128, 128, 128, 0, 0);
    ln_kernel<<<128, 128, 0, stream>>>(pre1, ln1_g, ln1_b, H1m);
    gemm_kernel<<<256, 256, 0, stream>>>(H1m, f_W1, nullptr, nullptr, f_b1, nullptr, F1, 128, 512, 128, 0, 1);
    gemm_kernel<<<64, 256, 0, stream>>>(F1, f_W2, nullptr, nullptr, f_b2, H1m, pre2, 128, 128, 512, 0, 0);
    ln_kernel<<<128, 128, 0, stream>>>(pre2, ln2_g, ln2_b, Wfm);

    // ---- decode ----
    decode_kernel<<<(NTt + 15) / 16, 256, 0, stream>>>(idx_i, idx_j, idx_k, U2b, Wfm, Vmat,
                                                       bias, (float*)d_out, NTt);
}

// Round 2
// 1230.994 us; speedup vs baseline: 1.5142x; 1.5142x over previous
//
#include <hip/hip_runtime.h>
#include <hip/hip_bf16.h>

#define D_DIM 128
#define KT 128
#define JF 64
#define WB_BLOCKS 256

typedef __attribute__((ext_vector_type(8))) short bf16x8;
typedef __attribute__((ext_vector_type(4))) float f32x4;

__device__ inline unsigned short f2b(float f) {
    __hip_bfloat16 h = __float2bfloat16(f);
    return *reinterpret_cast<unsigned short*>(&h);
}
__device__ inline float b2f(unsigned short u) {
    unsigned int x = ((unsigned int)u) << 16;
    return __uint_as_float(x);
}

// ---------------------------------------------------------------------------
// edge_pass (PROVEN 377us design, restored): wave per edge. Xi += edge_x row
// (global f32 atomics), Nmat32[i][k]++ (global u32 atomic), Xk/cntw
// LDS-privatized. Split into 2 half-range launches (~190us each) so any
// hidden kernel >190us surfaces in next round's top-5 profile.
// ---------------------------------------------------------------------------
__global__ void __launch_bounds__(256) edge_pass_kernel(
    const float* __restrict__ edge_x, const int* __restrict__ edge_i,
    const int* __restrict__ edge_k, float* __restrict__ Xi, float* __restrict__ Xk,
    unsigned* __restrict__ Nmat32, unsigned* __restrict__ cntw,
    long e0, long eEnd, int epb)
{
    __shared__ float xk_s[KT * JF];      // 32 KB
    __shared__ unsigned cw_s[KT];
    for (int t = threadIdx.x; t < KT * JF; t += 256) xk_s[t] = 0.f;
    if (threadIdx.x < KT) cw_s[threadIdx.x] = 0u;
    __syncthreads();
    const int wid = threadIdx.x >> 6, lane = threadIdx.x & 63;
    const long base = e0 + (long)blockIdx.x * epb;
    for (int c = wid; c < epb; c += 4) {
        long e = base + c;
        if (e >= eEnd) break;
        int i = edge_i[e], k = edge_k[e];
        float x = edge_x[e * 64 + lane];
        unsafeAtomicAdd(&Xi[(long)i * 64 + lane], x);
        unsafeAtomicAdd(&xk_s[k * 64 + lane], x);
        if (lane == 0) atomicAdd(&Nmat32[(long)i * 128 + k], 1u);
        if (lane == 1) atomicAdd(&cw_s[k], 1u);
    }
    __syncthreads();
    for (int t = threadIdx.x; t < KT * JF; t += 256) {
        float v = xk_s[t];
        if (v != 0.f) unsafeAtomicAdd(&Xk[t], v);
    }
    if (threadIdx.x < KT && cw_s[threadIdx.x]) atomicAdd(&cntw[threadIdx.x], cw_s[threadIdx.x]);
}

// cnt: per-row sum of Nmat32 -> cntraw/invcnt; convert to u8 Nmat8.
__global__ void __launch_bounds__(256) cnt_kernel(
    const unsigned* __restrict__ Nmat32, unsigned char* __restrict__ Nmat8,
    float* __restrict__ cntraw, float* __restrict__ invcnt, int nNodes)
{
    int row = blockIdx.x * 4 + (threadIdx.x >> 6);
    int lane = threadIdx.x & 63;
    if (row >= nNodes) return;
    uint2 v = *(const uint2*)&Nmat32[(long)row * 128 + lane * 2];
    unsigned s = v.x + v.y;
    #pragma unroll
    for (int o = 32; o; o >>= 1) s += __shfl_down(s, o, 64);
    uchar2 o2; o2.x = (unsigned char)v.x; o2.y = (unsigned char)v.y;
    *(uchar2*)&Nmat8[(long)row * 128 + lane * 2] = o2;
    if (lane == 0) {
        float c = (float)s;
        cntraw[row] = c;
        invcnt[row] = 1.f / fmaxf(c, 1.f);
    }
}

// u0cvt: fp32 -> bf16
__global__ void __launch_bounds__(256) u0cvt_kernel(
    const float* __restrict__ in, unsigned short* __restrict__ out, long n4)
{
    long i = (long)blockIdx.x * 256 + threadIdx.x;
    long stride = (long)gridDim.x * 256;
    for (; i < n4; i += stride) {
        float4 v = *(const float4*)&in[i * 4];
        ushort4 o = make_ushort4(f2b(v.x), f2b(v.y), f2b(v.z), f2b(v.w));
        *(ushort4*)&out[i * 4] = o;
    }
}

// ---------------------------------------------------------------------------
// prep: fused P2/P3/ebx/btprep. Bt[n][kk] (bf16, stride 320)
// ---------------------------------------------------------------------------
__global__ void prep_kernel(const float* __restrict__ uWt, const float* __restrict__ Wl,
                            const float* __restrict__ uWb, const float* __restrict__ ep_W,
                            const float* __restrict__ ep_b,
                            unsigned short* __restrict__ Bt, float* __restrict__ ebx)
{
    int idx = blockIdx.x * 256 + threadIdx.x;
    if (idx < 128 * 320) {
        int n = idx / 320, kk = idx - n * 320;
        float v;
        if (kk < 128) {
            v = uWt[kk * 128 + n];
        } else {
            const float* a = (kk < 256) ? (Wl + (kk - 128) * 128) : (ep_W + (kk - 256) * 128);
            float s = 0.f;
            #pragma unroll 8
            for (int j = 0; j < 128; ++j) s += a[j] * uWb[j * 128 + n];
            v = s;
        }
        Bt[idx] = f2b(v);
    } else if (idx < 128 * 320 + 128) {
        int n = idx - 128 * 320;
        float s = 0.f;
        #pragma unroll 8
        for (int j = 0; j < 128; ++j) s += ep_b[j] * uWb[j * 128 + n];
        ebx[n] = s;
    }
}

// ---------------------------------------------------------------------------
// layerA MFMA: U_out(bf16) = relu(A[128x320]@B[320x128] + ub + flag*ebx)
// ---------------------------------------------------------------------------
__global__ void __launch_bounds__(256) layerA_mfma(
    const unsigned short* __restrict__ U_in, const unsigned char* __restrict__ Nmat8,
    const float* __restrict__ Xi, const float* __restrict__ cntraw,
    const float* __restrict__ invcnt, const unsigned short* __restrict__ Bt,
    const float* __restrict__ ub_l, const float* __restrict__ ebx,
    unsigned short* __restrict__ U_out, int nNodes)
{
    __shared__ __align__(16) unsigned short A_s[128][40];
    __shared__ __align__(16) unsigned short B_s[128][40];
    const int tid = threadIdx.x;
    const int w = tid >> 6, lane = tid & 63;
    const int quad = lane >> 4, l16 = lane & 15;
    const int nodeBase = blockIdx.x * 128;
    f32x4 acc[2][8];
    #pragma unroll
    for (int a = 0; a < 2; ++a)
        #pragma unroll
        for (int b = 0; b < 8; ++b) acc[a][b] = (f32x4){0.f, 0.f, 0.f, 0.f};

    const int rr = tid >> 3;          // 0..31
    const int kc = (tid & 7) * 4;     // 0..28

    for (int ks = 0; ks < 10; ++ks) {
        const int k0 = ks * 32;
        __syncthreads();
        {
            int n = tid & 127, seg = tid >> 7;
            const unsigned short* src = Bt + n * 320 + k0 + seg * 16;
            uint4 p0 = *(const uint4*)(src);
            uint4 p1 = *(const uint4*)(src + 8);
            *(uint4*)&B_s[n][seg * 16]     = p0;
            *(uint4*)&B_s[n][seg * 16 + 8] = p1;
        }
        #pragma unroll
        for (int p = 0; p < 4; ++p) {
            int r = p * 32 + rr;
            int node = nodeBase + r;
            ushort4 w4 = make_ushort4(0, 0, 0, 0);
            if (node < nNodes) {
                if (ks < 4) {
                    w4 = *(const ushort4*)&U_in[(long)node * 128 + k0 + kc];
                } else if (ks < 8) {
                    float inv = invcnt[node];
                    const unsigned char* np_ = &Nmat8[(long)node * 128 + (k0 - 128) + kc];
                    w4 = make_ushort4(f2b((float)np_[0] * inv), f2b((float)np_[1] * inv),
                                      f2b((float)np_[2] * inv), f2b((float)np_[3] * inv));
                } else {
                    float inv = invcnt[node];
                    float4 x = *(const float4*)&Xi[(long)node * 64 + (k0 - 256) + kc];
                    w4 = make_ushort4(f2b(x.x * inv), f2b(x.y * inv),
                                      f2b(x.z * inv), f2b(x.w * inv));
                }
            }
            *(ushort4*)&A_s[r][kc] = w4;
        }
        __syncthreads();
        bf16x8 a0 = *(const bf16x8*)&A_s[w * 32 + l16][quad * 8];
        bf16x8 a1 = *(const bf16x8*)&A_s[w * 32 + 16 + l16][quad * 8];
        #pragma unroll
        for (int nt = 0; nt < 8; ++nt) {
            bf16x8 b = *(const bf16x8*)&B_s[nt * 16 + l16][quad * 8];
            acc[0][nt] = __builtin_amdgcn_mfma_f32_16x16x32_bf16(a0, b, acc[0][nt], 0, 0, 0);
            acc[1][nt] = __builtin_amdgcn_mfma_f32_16x16x32_bf16(a1, b, acc[1][nt], 0, 0, 0);
        }
    }
    #pragma unroll
    for (int mt = 0; mt < 2; ++mt) {
        #pragma unroll
        for (int r = 0; r < 4; ++r) {
            int row = w * 32 + mt * 16 + quad * 4 + r;
            int node = nodeBase + row;
            if (node < nNodes) {
                float flag = (cntraw[node] > 0.f) ? 1.f : 0.f;
                #pragma unroll
                for (int nt = 0; nt < 8; ++nt) {
                    int col = nt * 16 + l16;
                    float vv = acc[mt][nt][r] + ub_l[col] + flag * ebx[col];
                    U_out[(long)node * 128 + col] = f2b(fmaxf(vv, 0.f));
                }
            }
        }
    }
}

// ---------------------------------------------------------------------------
// wmsgB MFMA: partial[b] = N^T_chunk @ U_chunk
// ---------------------------------------------------------------------------
__global__ void __launch_bounds__(256) wmsgB_mfma(
    const unsigned short* __restrict__ U, const unsigned char* __restrict__ Nmat8,
    float* __restrict__ partial, int nodes_per_block, int nNodes)
{
    __shared__ __align__(16) unsigned short A_s[128][40];  // [ktok][node]
    __shared__ __align__(16) unsigned short B_s[128][40];  // [d][node]
    const int tid = threadIdx.x;
    const int w = tid >> 6, lane = tid & 63;
    const int quad = lane >> 4, l16 = lane & 15;
    f32x4 acc[2][8];
    #pragma unroll
    for (int a = 0; a < 2; ++a)
        #pragma unroll
        for (int b = 0; b < 8; ++b) acc[a][b] = (f32x4){0.f, 0.f, 0.f, 0.f};

    int base = blockIdx.x * nodes_per_block;
    int end = min(base + nodes_per_block, nNodes);
    const int nn = tid >> 3;          // 0..31
    const int cc = (tid & 7) * 16;    // 0..112
    for (int g = base; g < end; g += 32) {
        int cnt = min(32, end - g);
        __syncthreads();
        if (nn < cnt) {
            int node = g + nn;
            uint4 nb = *(const uint4*)&Nmat8[(long)node * 128 + cc];
            const unsigned char* nbp = (const unsigned char*)&nb;
            uint4 ua = *(const uint4*)&U[(long)node * 128 + cc];
            uint4 ubb = *(const uint4*)&U[(long)node * 128 + cc + 8];
            unsigned short uv[16];
            *(uint4*)&uv[0] = ua;
            *(uint4*)&uv[8] = ubb;
            #pragma unroll
            for (int j = 0; j < 16; ++j) {
                A_s[cc + j][nn] = f2b((float)nbp[j]);
                B_s[cc + j][nn] = uv[j];
            }
        } else {
            #pragma unroll
            for (int j = 0; j < 16; ++j) { A_s[cc + j][nn] = 0; B_s[cc + j][nn] = 0; }
        }
        __syncthreads();
        bf16x8 a0 = *(const bf16x8*)&A_s[w * 32 + l16][quad * 8];
        bf16x8 a1 = *(const bf16x8*)&A_s[w * 32 + 16 + l16][quad * 8];
        #pragma unroll
        for (int nt = 0; nt < 8; ++nt) {
            bf16x8 b = *(const bf16x8*)&B_s[nt * 16 + l16][quad * 8];
            acc[0][nt] = __builtin_amdgcn_mfma_f32_16x16x32_bf16(a0, b, acc[0][nt], 0, 0, 0);
            acc[1][nt] = __builtin_amdgcn_mfma_f32_16x16x32_bf16(a1, b, acc[1][nt], 0, 0, 0);
        }
    }
    float* my = partial + (size_t)blockIdx.x * 16384;
    #pragma unroll
    for (int mt = 0; mt < 2; ++mt)
        #pragma unroll
        for (int r = 0; r < 4; ++r) {
            int row = w * 32 + mt * 16 + quad * 4 + r;
            #pragma unroll
            for (int nt = 0; nt < 8; ++nt)
                my[row * 128 + nt * 16 + l16] = acc[mt][nt][r];
        }
}

// reduceP: 512 blocks = 64 idx-tiles x 8 partial-groups of 32; atomic flush
__global__ void __launch_bounds__(256) reduceP_kernel(
    const float* __restrict__ partial, float* __restrict__ Wmsg)
{
    int grp = blockIdx.x >> 6;          // 0..7
    int ib  = blockIdx.x & 63;          // 0..63
    int idx = ib * 256 + threadIdx.x;   // 0..16383
    float s = 0.f;
    #pragma unroll 8
    for (int b = 0; b < 32; ++b)
        s += partial[(size_t)(grp * 32 + b) * 16384 + idx];
    unsafeAtomicAdd(&Wmsg[idx], s);
}

// fused wmsg_fin + W-layer GEMM: one block per k-token row.
// W_out[kk][n] = relu(wb[n] + sum_k Wrow[kk][k]*wWt[k][n] + Wmsgn[kk][k]*wWb[k][n])
__global__ void __launch_bounds__(128) wfin_gemm_kernel(
    const float* __restrict__ Wmsg, const float* __restrict__ Xk,
    const unsigned* __restrict__ cntw, const float* __restrict__ ep_W,
    const float* __restrict__ ep_b, const float* __restrict__ Wrow,
    const float* __restrict__ wWt, const float* __restrict__ wWb,
    const float* __restrict__ wb_l, float* __restrict__ Wout)
{
    __shared__ float msg_s[128];
    __shared__ float a_s[128];
    const int kk = blockIdx.x, t = threadIdx.x;
    float c = (float)cntw[kk];
    {
        float s = Wmsg[kk * 128 + t];
        const float* xk = Xk + kk * 64;
        #pragma unroll 8
        for (int j = 0; j < 64; ++j) s += xk[j] * ep_W[j * 128 + t];
        s += c * ep_b[t];
        msg_s[t] = s / fmaxf(c, 1.f);
        a_s[t] = Wrow[kk * 128 + t];
    }
    __syncthreads();
    float s = wb_l[t];
    #pragma unroll 4
    for (int k = 0; k < 128; ++k) s += a_s[k] * wWt[k * 128 + t];
    #pragma unroll 4
    for (int k = 0; k < 128; ++k) s += msg_s[k] * wWb[k * 128 + t];
    Wout[kk * 128 + t] = fmaxf(s, 0.f);
}

__global__ void add_kernel(const float* __restrict__ A, const float* __restrict__ B,
                           float* __restrict__ C, int n)
{
    int i = blockIdx.x * 256 + threadIdx.x;
    if (i < n) C[i] = A[i] + B[i];
}

// fused Q/K/V projection: 128 tokens x 384 outputs
__global__ void qkv_kernel(const float* __restrict__ X,
                           const float* __restrict__ Wq, const float* __restrict__ Wk,
                           const float* __restrict__ Wv, const float* __restrict__ bq,
                           const float* __restrict__ bk, const float* __restrict__ bv,
                           float* __restrict__ qm, float* __restrict__ km, float* __restrict__ vm)
{
    int idx = blockIdx.x * 256 + threadIdx.x;
    if (idx >= 128 * 384) return;
    int m = idx / 384, c = idx - m * 384;
    int sel = c >> 7, n = c & 127;
    const float* W = (sel == 0) ? Wq : (sel == 1) ? Wk : Wv;
    const float* b = (sel == 0) ? bq : (sel == 1) ? bk : bv;
    float s = b[n];
    const float* x = X + m * 128;
    #pragma unroll 8
    for (int k = 0; k < 128; ++k) s += x[k] * W[k * 128 + n];
    float* o = (sel == 0) ? qm : (sel == 1) ? km : vm;
    o[m * 128 + n] = s;
}

__global__ void attn_kernel(const float* __restrict__ q, const float* __restrict__ kmat,
                            const float* __restrict__ vmat, float* __restrict__ outp)
{
    __shared__ float p_s[128];
    __shared__ float red_s[4];
    const int tok = blockIdx.x;
    const int t = threadIdx.x;
    const int lane = t & 63, wid = t >> 6;
    for (int h = 0; h < 2; ++h) {
        const float* qr = q + tok * 128 + h * 64;
        const float* kr = kmat + t * 128 + h * 64;
        float s = 0.f;
        #pragma unroll
        for (int d = 0; d < 64; ++d) s += qr[d] * kr[d];
        s *= 0.125f;
        float m = s;
        #pragma unroll
        for (int o = 32; o; o >>= 1) m = fmaxf(m, __shfl_down(m, o, 64));
        if (lane == 0) red_s[wid] = m;
        __syncthreads();
        m = fmaxf(red_s[0], red_s[1]);
        float ev = expf(s - m);
        float ss = ev;
        #pragma unroll
        for (int o = 32; o; o >>= 1) ss += __shfl_down(ss, o, 64);
        if (lane == 0) red_s[2 + wid] = ss;
        __syncthreads();
        float tot = red_s[2] + red_s[3];
        p_s[t] = ev / tot;
        __syncthreads();
        if (t < 64) {
            float o = 0.f;
            #pragma unroll 8
            for (int j = 0; j < 128; ++j) o += p_s[j] * vmat[j * 128 + h * 64 + t];
            outp[tok * 128 + h * 64 + t] = o;
        }
        __syncthreads();
    }
}

// fused attn-out projection + residual + LN1: one block (128 thr) per token
__global__ void __launch_bounds__(128) proj_ln_kernel(
    const float* __restrict__ attnO, const float* __restrict__ Wo,
    const float* __restrict__ bo, const float* __restrict__ Xmat,
    const float* __restrict__ g, const float* __restrict__ b, float* __restrict__ H1)
{
    __shared__ float a_s[128];
    __shared__ float red_s[4];
    const int m = blockIdx.x, t = threadIdx.x, lane = t & 63, wid = t >> 6;
    a_s[t] = attnO[m * 128 + t];
    __syncthreads();
    float v = bo[t];
    #pragma unroll 4
    for (int k = 0; k < 128; ++k) v += a_s[k] * Wo[k * 128 + t];
    v += Xmat[m * 128 + t];
    // LN
    float s = v;
    #pragma unroll
    for (int o = 32; o; o >>= 1) s += __shfl_down(s, o, 64);
    if (lane == 0) red_s[wid] = s;
    __syncthreads();
    float mean = (red_s[0] + red_s[1]) * (1.f / 128.f);
    float d = v - mean;
    float q2 = d * d;
    #pragma unroll
    for (int o = 32; o; o >>= 1) q2 += __shfl_down(q2, o, 64);
    if (lane == 0) red_s[2 + wid] = q2;
    __syncthreads();
    float var = (red_s[2] + red_s[3]) * (1.f / 128.f);
    H1[m * 128 + t] = d * rsqrtf(var + 1e-5f) * g[t] + b[t];
}

// fused FFN (W1+relu, W2) + residual + LN2: one block (128 thr) per token
__global__ void __launch_bounds__(128) ffn_ln_kernel(
    const float* __restrict__ H1, const float* __restrict__ f_W1,
    const float* __restrict__ f_b1, const float* __restrict__ f_W2,
    const float* __restrict__ f_b2, const float* __restrict__ g,
    const float* __restrict__ b, float* __restrict__ Wf)
{
    __shared__ float h_s[128];
    __shared__ float f_s[512];
    __shared__ float red_s[4];
    const int m = blockIdx.x, t = threadIdx.x, lane = t & 63, wid = t >> 6;
    h_s[t] = H1[m * 128 + t];
    __syncthreads();
    #pragma unroll
    for (int nn = 0; nn < 4; ++nn) {
        int n = t + nn * 128;
        float s = f_b1[n];
        #pragma unroll 4
        for (int k = 0; k < 128; ++k) s += h_s[k] * f_W1[k * 512 + n];
        f_s[n] = fmaxf(s, 0.f);
    }
    __syncthreads();
    float v = f_b2[t];
    #pragma unroll 4
    for (int k = 0; k < 512; ++k) v += f_s[k] * f_W2[k * 128 + t];
    v += h_s[t];
    // LN
    float s = v;
    #pragma unroll
    for (int o = 32; o; o >>= 1) s += __shfl_down(s, o, 64);
    if (lane == 0) red_s[wid] = s;
    __syncthreads();
    float mean = (red_s[0] + red_s[1]) * (1.f / 128.f);
    float d = v - mean;
    float q2 = d * d;
    #pragma unroll
    for (int o = 32; o; o >>= 1) q2 += __shfl_down(q2, o, 64);
    if (lane == 0) red_s[2 + wid] = q2;
    __syncthreads();
    float var = (red_s[2] + red_s[3]) * (1.f / 128.f);
    Wf[m * 128 + t] = d * rsqrtf(var + 1e-5f) * g[t] + b[t];
}

// decode: 16 lanes per triple; U2 bf16 rows (16B/lane), Wf/V fp32
__global__ void __launch_bounds__(256) decode_kernel(
    const int* __restrict__ idx_i, const int* __restrict__ idx_j, const int* __restrict__ idx_k,
    const unsigned short* __restrict__ U2, const float* __restrict__ Wf, const float* __restrict__ V,
    const float* __restrict__ bias, float* __restrict__ out, int n)
{
    const int g = threadIdx.x >> 4;      // 0..15
    const int hl = threadIdx.x & 15;
    int t = blockIdx.x * 16 + g;
    if (t >= n) return;
    int i = idx_i[t], j = idx_j[t], kk = idx_k[t];
    const unsigned short* up = U2 + (long)i * 128 + hl * 8;
    const float* wp = Wf + kk * 128 + hl * 8;
    const float* vp = V + j * 128 + hl * 8;
    uint4 ur = *(const uint4*)up;                 // 8 bf16
    const unsigned short* uu = (const unsigned short*)&ur;
    float4 w0 = *(const float4*)wp,  w1 = *(const float4*)(wp + 4);
    float4 v0 = *(const float4*)vp,  v1 = *(const float4*)(vp + 4);
    float s = b2f(uu[0]) * w0.x * v0.x + b2f(uu[1]) * w0.y * v0.y
            + b2f(uu[2]) * w0.z * v0.z + b2f(uu[3]) * w0.w * v0.w
            + b2f(uu[4]) * w1.x * v1.x + b2f(uu[5]) * w1.y * v1.y
            + b2f(uu[6]) * w1.z * v1.z + b2f(uu[7]) * w1.w * v1.w;
    #pragma unroll
    for (int o = 8; o; o >>= 1) s += __shfl_down(s, o, 16);
    if (hl == 0) out[t] = 1.f / (1.f + expf(-(s + bias[0])));
}

// ---------------------------------------------------------------------------
extern "C" void kernel_launch(void* const* d_in, const int* in_sizes, int n_in,
                              void* d_out, int out_size, void* d_ws, size_t ws_size,
                              hipStream_t stream)
{
    const float* edge_x = (const float*)d_in[0];
    const int*   edge_i = (const int*)d_in[1];
    const int*   edge_k = (const int*)d_in[2];
    const int*   idx_i  = (const int*)d_in[3];
    const int*   idx_j  = (const int*)d_in[4];
    const int*   idx_k  = (const int*)d_in[5];
    const float* u0   = (const float*)d_in[6];
    const float* w0   = (const float*)d_in[7];
    const float* ep_W = (const float*)d_in[8];
    const float* ep_b = (const float*)d_in[9];
    const float* uW   = (const float*)d_in[10];
    const float* ub   = (const float*)d_in[11];
    const float* wW   = (const float*)d_in[12];
    const float* wb   = (const float*)d_in[13];
    const float* pos  = (const float*)d_in[14];
    const float* Wq = (const float*)d_in[15];
    const float* Wk = (const float*)d_in[16];
    const float* Wv = (const float*)d_in[17];
    const float* bq = (const float*)d_in[18];
    const float* bk = (const float*)d_in[19];
    const float* bv = (const float*)d_in[20];
    const float* Wo = (const float*)d_in[21];
    const float* bo = (const float*)d_in[22];
    const float* ln1_g = (const float*)d_in[23];
    const float* ln1_b = (const float*)d_in[24];
    const float* f_W1 = (const float*)d_in[25];
    const float* f_b1 = (const float*)d_in[26];
    const float* f_W2 = (const float*)d_in[27];
    const float* f_b2 = (const float*)d_in[28];
    const float* ln2_g = (const float*)d_in[29];
    const float* ln2_b = (const float*)d_in[30];
    const float* Vmat = (const float*)d_in[31];
    const float* bias = (const float*)d_in[32];

    const int E   = in_sizes[1];
    const int NTt = in_sizes[3];
    const int nNodes = in_sizes[6] / D_DIM;

    char* ws = (char*)d_ws;
    size_t off = 0;
    auto alloc = [&](size_t bytes) -> char* {
        char* p = ws + off;
        off = (off + bytes + 255) & ~(size_t)255;
        return p;
    };
    // zero-initialized region first (single memset)
    unsigned* Nmat32 = (unsigned*)alloc((size_t)nNodes * 128 * 4);
    float*    Xi     = (float*)alloc((size_t)nNodes * 64 * 4);
    float*    Xkseg  = (float*)alloc(128 * 64 * 4);
    unsigned* cntw   = (unsigned*)alloc(512);
    float*    Wmsg0  = (float*)alloc(65536);
    float*    Wmsg1  = (float*)alloc(65536);
    size_t zeroBytes = off;
    // rest (written before read)
    unsigned char* Nmat8 = (unsigned char*)alloc((size_t)nNodes * 128);
    float* cntraw = (float*)alloc((size_t)nNodes * 4);
    float* invcnt = (float*)alloc((size_t)nNodes * 4);
    unsigned short* U0b = (unsigned short*)alloc((size_t)nNodes * 128 * 2);
    unsigned short* U1b = (unsigned short*)alloc((size_t)nNodes * 128 * 2);
    unsigned short* U2b = (unsigned short*)alloc((size_t)nNodes * 128 * 2);
    float* partials = (float*)alloc((size_t)WB_BLOCKS * 16384 * 4);
    unsigned short* Bt0 = (unsigned short*)alloc(128 * 320 * 2);
    unsigned short* Bt1 = (unsigned short*)alloc(128 * 320 * 2);
    float* W1 = (float*)alloc(65536);
    float* W2 = (float*)alloc(65536);
    float* ebx0 = (float*)alloc(512);
    float* ebx1 = (float*)alloc(512);
    float* Xmat  = (float*)alloc(65536);
    float* qm    = (float*)alloc(65536);
    float* km    = (float*)alloc(65536);
    float* vm    = (float*)alloc(65536);
    float* attnO = (float*)alloc(65536);
    float* H1m   = (float*)alloc(65536);
    float* Wfm   = (float*)alloc(65536);

    const float* uWt0 = uW;
    const float* uWb0 = uW + 128 * 128;
    const float* uWt1 = uW + 256 * 128;
    const float* uWb1 = uW + 256 * 128 + 128 * 128;
    const float* wWt0 = wW;
    const float* wWb0 = wW + 128 * 128;
    const float* wWt1 = wW + 256 * 128;
    const float* wWb1 = wW + 256 * 128 + 128 * 128;

    hipMemsetAsync(d_ws, 0, zeroBytes, stream);

    // ---- edge pass (split in two ~190us halves; same total block count) ----
    long half = E >> 1;
    int epb0 = (int)((half + 511) / 512);
    int epb1 = (int)((E - half + 511) / 512);
    edge_pass_kernel<<<512, 256, 0, stream>>>(edge_x, edge_i, edge_k, Xi, Xkseg,
                                              Nmat32, cntw, 0, half, epb0);
    edge_pass_kernel<<<512, 256, 0, stream>>>(edge_x, edge_i, edge_k, Xi, Xkseg,
                                              Nmat32, cntw, half, E, epb1);
    cnt_kernel<<<(nNodes + 3) / 4, 256, 0, stream>>>(Nmat32, Nmat8, cntraw, invcnt, nNodes);
    u0cvt_kernel<<<1024, 256, 0, stream>>>(u0, U0b, (long)nNodes * 32);

    int npb = (nNodes + WB_BLOCKS - 1) / WB_BLOCKS;
    int la_grid = (nNodes + 127) / 128;

    // ---- layer 0 ----
    prep_kernel<<<161, 256, 0, stream>>>(uWt0, w0, uWb0, ep_W, ep_b, Bt0, ebx0);
    wmsgB_mfma<<<WB_BLOCKS, 256, 0, stream>>>(U0b, Nmat8, partials, npb, nNodes);
    reduceP_kernel<<<512, 256, 0, stream>>>(partials, Wmsg0);
    layerA_mfma<<<la_grid, 256, 0, stream>>>(U0b, Nmat8, Xi, cntraw, invcnt, Bt0, ub, ebx0, U1b, nNodes);
    wfin_gemm_kernel<<<128, 128, 0, stream>>>(Wmsg0, Xkseg, cntw, ep_W, ep_b,
                                              w0, wWt0, wWb0, wb, W1);

    // ---- layer 1 ----
    prep_kernel<<<161, 256, 0, stream>>>(uWt1, W1, uWb1, ep_W, ep_b, Bt1, ebx1);
    wmsgB_mfma<<<WB_BLOCKS, 256, 0, stream>>>(U1b, Nmat8, partials, npb, nNodes);
    reduceP_kernel<<<512, 256, 0, stream>>>(partials, Wmsg1);
    layerA_mfma<<<la_grid, 256, 0, stream>>>(U1b, Nmat8, Xi, cntraw, invcnt, Bt1, ub + 128, ebx1, U2b, nNodes);
    wfin_gemm_kernel<<<128, 128, 0, stream>>>(Wmsg1, Xkseg, cntw, ep_W, ep_b,
                                              W1, wWt1, wWb1, wb + 128, W2);

    // ---- TimeRefine ----
    add_kernel<<<64, 256, 0, stream>>>(W2, pos, Xmat, 128 * 128);
    qkv_kernel<<<192, 256, 0, stream>>>(Xmat, Wq, Wk, Wv, bq, bk, bv, qm, km, vm);
    attn_kernel<<<128, 128, 0, stream>>>(qm, km, vm, attnO);
    proj_ln_kernel<<<128, 128, 0, stream>>>(attnO, Wo, bo, Xmat, ln1_g, ln1_b, H1m);
    ffn_ln_kernel<<<128, 128, 0, stream>>>(H1m, f_W1, f_b1, f_W2, f_b2, ln2_g, ln2_b, Wfm);

    // ---- decode ----
    decode_kernel<<<(NTt + 15) / 16, 256, 0, stream>>>(idx_i, idx_j, idx_k, U2b, Wfm, Vmat,
                                                       bias, (float*)d_out, NTt);
}

// Round 3
// 1138.921 us; speedup vs baseline: 1.6366x; 1.0808x over previous
//
#include <hip/hip_runtime.h>
#include <hip/hip_bf16.h>

#define D_DIM 128
#define KT 128
#define JF 64
#define WB_BLOCKS 256

typedef __attribute__((ext_vector_type(8))) short bf16x8;
typedef __attribute__((ext_vector_type(4))) float f32x4;

__device__ inline unsigned short f2b(float f) {
    __hip_bfloat16 h = __float2bfloat16(f);
    return *reinterpret_cast<unsigned short*>(&h);
}
__device__ inline float b2f(unsigned short u) {
    unsigned int x = ((unsigned int)u) << 16;
    return __uint_as_float(x);
}

// ---------------------------------------------------------------------------
// edge_pass (single 1024-block launch — splitting costs 93us of atomic
// concurrency). N counts packed u8x4-in-u32 atomics directly into Nmat8.
// ---------------------------------------------------------------------------
__global__ void __launch_bounds__(256) edge_pass_kernel(
    const float* __restrict__ edge_x, const int* __restrict__ edge_i,
    const int* __restrict__ edge_k, float* __restrict__ Xi, float* __restrict__ Xk,
    unsigned* __restrict__ NmatP, unsigned* __restrict__ cntw, int E, int epb)
{
    __shared__ float xk_s[KT * JF];      // 32 KB
    __shared__ unsigned cw_s[KT];
    for (int t = threadIdx.x; t < KT * JF; t += 256) xk_s[t] = 0.f;
    if (threadIdx.x < KT) cw_s[threadIdx.x] = 0u;
    __syncthreads();
    const int wid = threadIdx.x >> 6, lane = threadIdx.x & 63;
    const long base = (long)blockIdx.x * epb;
    for (int c = wid; c < epb; c += 4) {
        long e = base + c;
        if (e >= (long)E) break;
        int i = edge_i[e], k = edge_k[e];
        float x = edge_x[e * 64 + lane];
        unsafeAtomicAdd(&Xi[(long)i * 64 + lane], x);
        unsafeAtomicAdd(&xk_s[k * 64 + lane], x);
        if (lane == 0) atomicAdd(&NmatP[(long)i * 32 + (k >> 2)], 1u << ((k & 3) * 8));
        if (lane == 1) atomicAdd(&cw_s[k], 1u);
    }
    __syncthreads();
    for (int t = threadIdx.x; t < KT * JF; t += 256) {
        float v = xk_s[t];
        if (v != 0.f) unsafeAtomicAdd(&Xk[t], v);
    }
    if (threadIdx.x < KT && cw_s[threadIdx.x]) atomicAdd(&cntw[threadIdx.x], cw_s[threadIdx.x]);
}

// ---------------------------------------------------------------------------
// mid_kernel: fused {cnt rowsum} + {u0->bf16 cvt} + {prep layer0}.
// Block-range dispatch: [0,cntB) cnt, [cntB,cntB+1024) cvt, rest prep.
// ---------------------------------------------------------------------------
__global__ void __launch_bounds__(256) mid_kernel(
    const unsigned* __restrict__ NmatP, float* __restrict__ cntraw,
    float* __restrict__ invcnt, int nNodes, int cntB,
    const float* __restrict__ u0, unsigned short* __restrict__ U0b, long n4,
    const float* __restrict__ uWt, const float* __restrict__ Wl,
    const float* __restrict__ uWb, const float* __restrict__ ep_W,
    const float* __restrict__ ep_b,
    unsigned short* __restrict__ Bt, float* __restrict__ ebx)
{
    const int bid = blockIdx.x;
    if (bid < cntB) {
        // per-node edge count from packed u8 Nmat: wave per row, lanes 0..31
        int row = bid * 4 + (threadIdx.x >> 6);
        int lane = threadIdx.x & 63;
        if (row < nNodes && lane < 32) {
            unsigned wv = NmatP[(long)row * 32 + lane];
            unsigned s = (wv & 0xFF) + ((wv >> 8) & 0xFF) + ((wv >> 16) & 0xFF) + (wv >> 24);
            #pragma unroll
            for (int o = 16; o; o >>= 1) s += __shfl_down(s, o, 32);
            if (lane == 0) {
                float c = (float)s;
                cntraw[row] = c;
                invcnt[row] = 1.f / fmaxf(c, 1.f);
            }
        }
    } else if (bid < cntB + 1024) {
        long i = (long)(bid - cntB) * 256 + threadIdx.x;
        long stride = (long)1024 * 256;
        for (; i < n4; i += stride) {
            float4 v = *(const float4*)&u0[i * 4];
            ushort4 o = make_ushort4(f2b(v.x), f2b(v.y), f2b(v.z), f2b(v.w));
            *(ushort4*)&U0b[i * 4] = o;
        }
    } else {
        int idx = (bid - cntB - 1024) * 256 + threadIdx.x;
        if (idx < 128 * 320) {
            int n = idx / 320, kk = idx - n * 320;
            float v;
            if (kk < 128) {
                v = uWt[kk * 128 + n];
            } else {
                const float* a = (kk < 256) ? (Wl + (kk - 128) * 128) : (ep_W + (kk - 256) * 128);
                float s = 0.f;
                #pragma unroll 8
                for (int j = 0; j < 128; ++j) s += a[j] * uWb[j * 128 + n];
                v = s;
            }
            Bt[idx] = f2b(v);
        } else if (idx < 128 * 320 + 128) {
            int n = idx - 128 * 320;
            float s = 0.f;
            #pragma unroll 8
            for (int j = 0; j < 128; ++j) s += ep_b[j] * uWb[j * 128 + n];
            ebx[n] = s;
        }
    }
}

// prep (layer1 only; layer0's lives in mid_kernel)
__global__ void prep_kernel(const float* __restrict__ uWt, const float* __restrict__ Wl,
                            const float* __restrict__ uWb, const float* __restrict__ ep_W,
                            const float* __restrict__ ep_b,
                            unsigned short* __restrict__ Bt, float* __restrict__ ebx)
{
    int idx = blockIdx.x * 256 + threadIdx.x;
    if (idx < 128 * 320) {
        int n = idx / 320, kk = idx - n * 320;
        float v;
        if (kk < 128) {
            v = uWt[kk * 128 + n];
        } else {
            const float* a = (kk < 256) ? (Wl + (kk - 128) * 128) : (ep_W + (kk - 256) * 128);
            float s = 0.f;
            #pragma unroll 8
            for (int j = 0; j < 128; ++j) s += a[j] * uWb[j * 128 + n];
            v = s;
        }
        Bt[idx] = f2b(v);
    } else if (idx < 128 * 320 + 128) {
        int n = idx - 128 * 320;
        float s = 0.f;
        #pragma unroll 8
        for (int j = 0; j < 128; ++j) s += ep_b[j] * uWb[j * 128 + n];
        ebx[n] = s;
    }
}

// ---------------------------------------------------------------------------
// layerA MFMA: U_out(bf16) = relu(A[128x320]@B[320x128] + ub + flag*ebx)
// ---------------------------------------------------------------------------
__global__ void __launch_bounds__(256) layerA_mfma(
    const unsigned short* __restrict__ U_in, const unsigned char* __restrict__ Nmat8,
    const float* __restrict__ Xi, const float* __restrict__ cntraw,
    const float* __restrict__ invcnt, const unsigned short* __restrict__ Bt,
    const float* __restrict__ ub_l, const float* __restrict__ ebx,
    unsigned short* __restrict__ U_out, int nNodes)
{
    __shared__ __align__(16) unsigned short A_s[128][40];
    __shared__ __align__(16) unsigned short B_s[128][40];
    const int tid = threadIdx.x;
    const int w = tid >> 6, lane = tid & 63;
    const int quad = lane >> 4, l16 = lane & 15;
    const int nodeBase = blockIdx.x * 128;
    f32x4 acc[2][8];
    #pragma unroll
    for (int a = 0; a < 2; ++a)
        #pragma unroll
        for (int b = 0; b < 8; ++b) acc[a][b] = (f32x4){0.f, 0.f, 0.f, 0.f};

    const int rr = tid >> 3;          // 0..31
    const int kc = (tid & 7) * 4;     // 0..28

    for (int ks = 0; ks < 10; ++ks) {
        const int k0 = ks * 32;
        __syncthreads();
        {
            int n = tid & 127, seg = tid >> 7;
            const unsigned short* src = Bt + n * 320 + k0 + seg * 16;
            uint4 p0 = *(const uint4*)(src);
            uint4 p1 = *(const uint4*)(src + 8);
            *(uint4*)&B_s[n][seg * 16]     = p0;
            *(uint4*)&B_s[n][seg * 16 + 8] = p1;
        }
        #pragma unroll
        for (int p = 0; p < 4; ++p) {
            int r = p * 32 + rr;
            int node = nodeBase + r;
            ushort4 w4 = make_ushort4(0, 0, 0, 0);
            if (node < nNodes) {
                if (ks < 4) {
                    w4 = *(const ushort4*)&U_in[(long)node * 128 + k0 + kc];
                } else if (ks < 8) {
                    float inv = invcnt[node];
                    const unsigned char* np_ = &Nmat8[(long)node * 128 + (k0 - 128) + kc];
                    w4 = make_ushort4(f2b((float)np_[0] * inv), f2b((float)np_[1] * inv),
                                      f2b((float)np_[2] * inv), f2b((float)np_[3] * inv));
                } else {
                    float inv = invcnt[node];
                    float4 x = *(const float4*)&Xi[(long)node * 64 + (k0 - 256) + kc];
                    w4 = make_ushort4(f2b(x.x * inv), f2b(x.y * inv),
                                      f2b(x.z * inv), f2b(x.w * inv));
                }
            }
            *(ushort4*)&A_s[r][kc] = w4;
        }
        __syncthreads();
        bf16x8 a0 = *(const bf16x8*)&A_s[w * 32 + l16][quad * 8];
        bf16x8 a1 = *(const bf16x8*)&A_s[w * 32 + 16 + l16][quad * 8];
        #pragma unroll
        for (int nt = 0; nt < 8; ++nt) {
            bf16x8 b = *(const bf16x8*)&B_s[nt * 16 + l16][quad * 8];
            acc[0][nt] = __builtin_amdgcn_mfma_f32_16x16x32_bf16(a0, b, acc[0][nt], 0, 0, 0);
            acc[1][nt] = __builtin_amdgcn_mfma_f32_16x16x32_bf16(a1, b, acc[1][nt], 0, 0, 0);
        }
    }
    #pragma unroll
    for (int mt = 0; mt < 2; ++mt) {
        #pragma unroll
        for (int r = 0; r < 4; ++r) {
            int row = w * 32 + mt * 16 + quad * 4 + r;
            int node = nodeBase + row;
            if (node < nNodes) {
                float flag = (cntraw[node] > 0.f) ? 1.f : 0.f;
                #pragma unroll
                for (int nt = 0; nt < 8; ++nt) {
                    int col = nt * 16 + l16;
                    float vv = acc[mt][nt][r] + ub_l[col] + flag * ebx[col];
                    U_out[(long)node * 128 + col] = f2b(fmaxf(vv, 0.f));
                }
            }
        }
    }
}

// ---------------------------------------------------------------------------
// wmsgB MFMA: partial[b] = N^T_chunk @ U_chunk
// ---------------------------------------------------------------------------
__global__ void __launch_bounds__(256) wmsgB_mfma(
    const unsigned short* __restrict__ U, const unsigned char* __restrict__ Nmat8,
    float* __restrict__ partial, int nodes_per_block, int nNodes)
{
    __shared__ __align__(16) unsigned short A_s[128][40];  // [ktok][node]
    __shared__ __align__(16) unsigned short B_s[128][40];  // [d][node]
    const int tid = threadIdx.x;
    const int w = tid >> 6, lane = tid & 63;
    const int quad = lane >> 4, l16 = lane & 15;
    f32x4 acc[2][8];
    #pragma unroll
    for (int a = 0; a < 2; ++a)
        #pragma unroll
        for (int b = 0; b < 8; ++b) acc[a][b] = (f32x4){0.f, 0.f, 0.f, 0.f};

    int base = blockIdx.x * nodes_per_block;
    int end = min(base + nodes_per_block, nNodes);
    const int nn = tid >> 3;          // 0..31
    const int cc = (tid & 7) * 16;    // 0..112
    for (int g = base; g < end; g += 32) {
        int cnt = min(32, end - g);
        __syncthreads();
        if (nn < cnt) {
            int node = g + nn;
            uint4 nb = *(const uint4*)&Nmat8[(long)node * 128 + cc];
            const unsigned char* nbp = (const unsigned char*)&nb;
            uint4 ua = *(const uint4*)&U[(long)node * 128 + cc];
            uint4 ubb = *(const uint4*)&U[(long)node * 128 + cc + 8];
            unsigned short uv[16];
            *(uint4*)&uv[0] = ua;
            *(uint4*)&uv[8] = ubb;
            #pragma unroll
            for (int j = 0; j < 16; ++j) {
                A_s[cc + j][nn] = f2b((float)nbp[j]);
                B_s[cc + j][nn] = uv[j];
            }
        } else {
            #pragma unroll
            for (int j = 0; j < 16; ++j) { A_s[cc + j][nn] = 0; B_s[cc + j][nn] = 0; }
        }
        __syncthreads();
        bf16x8 a0 = *(const bf16x8*)&A_s[w * 32 + l16][quad * 8];
        bf16x8 a1 = *(const bf16x8*)&A_s[w * 32 + 16 + l16][quad * 8];
        #pragma unroll
        for (int nt = 0; nt < 8; ++nt) {
            bf16x8 b = *(const bf16x8*)&B_s[nt * 16 + l16][quad * 8];
            acc[0][nt] = __builtin_amdgcn_mfma_f32_16x16x32_bf16(a0, b, acc[0][nt], 0, 0, 0);
            acc[1][nt] = __builtin_amdgcn_mfma_f32_16x16x32_bf16(a1, b, acc[1][nt], 0, 0, 0);
        }
    }
    float* my = partial + (size_t)blockIdx.x * 16384;
    #pragma unroll
    for (int mt = 0; mt < 2; ++mt)
        #pragma unroll
        for (int r = 0; r < 4; ++r) {
            int row = w * 32 + mt * 16 + quad * 4 + r;
            #pragma unroll
            for (int nt = 0; nt < 8; ++nt)
                my[row * 128 + nt * 16 + l16] = acc[mt][nt][r];
        }
}

// fused partial-reduce + wmsg_fin + W-layer GEMM: one block per k-token row.
__global__ void __launch_bounds__(128) wfin_gemm_kernel(
    const float* __restrict__ partial, const float* __restrict__ Xk,
    const unsigned* __restrict__ cntw, const float* __restrict__ ep_W,
    const float* __restrict__ ep_b, const float* __restrict__ Wrow,
    const float* __restrict__ wWt, const float* __restrict__ wWb,
    const float* __restrict__ wb_l, float* __restrict__ Wout)
{
    __shared__ float msg_s[128];
    __shared__ float a_s[128];
    const int kk = blockIdx.x, t = threadIdx.x;
    float c = (float)cntw[kk];
    {
        float s = 0.f;
        const float* pp = partial + kk * 128 + t;
        #pragma unroll 8
        for (int b = 0; b < WB_BLOCKS; ++b) s += pp[(size_t)b * 16384];
        const float* xk = Xk + kk * 64;
        #pragma unroll 8
        for (int j = 0; j < 64; ++j) s += xk[j] * ep_W[j * 128 + t];
        s += c * ep_b[t];
        msg_s[t] = s / fmaxf(c, 1.f);
        a_s[t] = Wrow[kk * 128 + t];
    }
    __syncthreads();
    float s = wb_l[t];
    #pragma unroll 4
    for (int k = 0; k < 128; ++k) s += a_s[k] * wWt[k * 128 + t];
    #pragma unroll 4
    for (int k = 0; k < 128; ++k) s += msg_s[k] * wWb[k * 128 + t];
    Wout[kk * 128 + t] = fmaxf(s, 0.f);
}

// fused (W2+pos) + Q/K/V projection: 128 tokens x 384 outputs
__global__ void qkvf_kernel(const float* __restrict__ W2, const float* __restrict__ pos,
                            const float* __restrict__ Wq, const float* __restrict__ Wk,
                            const float* __restrict__ Wv, const float* __restrict__ bq,
                            const float* __restrict__ bk, const float* __restrict__ bv,
                            float* __restrict__ Xmat,
                            float* __restrict__ qm, float* __restrict__ km, float* __restrict__ vm)
{
    int idx = blockIdx.x * 256 + threadIdx.x;
    if (idx >= 128 * 384) return;
    int m = idx / 384, c = idx - m * 384;
    int sel = c >> 7, n = c & 127;
    const float* W = (sel == 0) ? Wq : (sel == 1) ? Wk : Wv;
    const float* b = (sel == 0) ? bq : (sel == 1) ? bk : bv;
    float s = b[n];
    const float* x2 = W2 + m * 128;
    const float* xp = pos + m * 128;
    #pragma unroll 8
    for (int k = 0; k < 128; ++k) s += (x2[k] + xp[k]) * W[k * 128 + n];
    float* o = (sel == 0) ? qm : (sel == 1) ? km : vm;
    o[m * 128 + n] = s;
    if (sel == 0) Xmat[m * 128 + n] = x2[n] + xp[n];
}

// fused attention + out-proj + LN1 + FFN + LN2: one block (128 thr) per token
__global__ void __launch_bounds__(128) attn_tail_kernel(
    const float* __restrict__ q, const float* __restrict__ kmat,
    const float* __restrict__ vmat, const float* __restrict__ Wo,
    const float* __restrict__ bo, const float* __restrict__ Xmat,
    const float* __restrict__ ln1_g, const float* __restrict__ ln1_b,
    const float* __restrict__ f_W1, const float* __restrict__ f_b1,
    const float* __restrict__ f_W2, const float* __restrict__ f_b2,
    const float* __restrict__ ln2_g, const float* __restrict__ ln2_b,
    float* __restrict__ Wf)
{
    __shared__ float p_s[128];
    __shared__ float a_s[128];
    __shared__ float h1_s[128];
    __shared__ float f_s[512];
    __shared__ float red_s[4];
    const int tok = blockIdx.x;
    const int t = threadIdx.x;
    const int lane = t & 63, wid = t >> 6;
    // ---- attention (2 heads), output row kept in a_s ----
    for (int h = 0; h < 2; ++h) {
        const float* qr = q + tok * 128 + h * 64;
        const float* kr = kmat + t * 128 + h * 64;
        float s = 0.f;
        #pragma unroll
        for (int d = 0; d < 64; ++d) s += qr[d] * kr[d];
        s *= 0.125f;
        float m = s;
        #pragma unroll
        for (int o = 32; o; o >>= 1) m = fmaxf(m, __shfl_down(m, o, 64));
        if (lane == 0) red_s[wid] = m;
        __syncthreads();
        m = fmaxf(red_s[0], red_s[1]);
        float ev = expf(s - m);
        float ss = ev;
        #pragma unroll
        for (int o = 32; o; o >>= 1) ss += __shfl_down(ss, o, 64);
        if (lane == 0) red_s[2 + wid] = ss;
        __syncthreads();
        float tot = red_s[2] + red_s[3];
        p_s[t] = ev / tot;
        __syncthreads();
        if (t < 64) {
            float o = 0.f;
            #pragma unroll 8
            for (int j = 0; j < 128; ++j) o += p_s[j] * vmat[j * 128 + h * 64 + t];
            a_s[h * 64 + t] = o;
        }
        __syncthreads();
    }
    // ---- out-proj + residual + LN1 -> h1_s ----
    {
        float v = bo[t];
        #pragma unroll 4
        for (int k = 0; k < 128; ++k) v += a_s[k] * Wo[k * 128 + t];
        v += Xmat[tok * 128 + t];
        float s = v;
        #pragma unroll
        for (int o = 32; o; o >>= 1) s += __shfl_down(s, o, 64);
        if (lane == 0) red_s[wid] = s;
        __syncthreads();
        float mean = (red_s[0] + red_s[1]) * (1.f / 128.f);
        float d = v - mean;
        float q2 = d * d;
        #pragma unroll
        for (int o = 32; o; o >>= 1) q2 += __shfl_down(q2, o, 64);
        if (lane == 0) red_s[2 + wid] = q2;
        __syncthreads();
        float var = (red_s[2] + red_s[3]) * (1.f / 128.f);
        h1_s[t] = d * rsqrtf(var + 1e-5f) * ln1_g[t] + ln1_b[t];
        __syncthreads();
    }
    // ---- FFN + residual + LN2 -> Wf ----
    #pragma unroll
    for (int nn = 0; nn < 4; ++nn) {
        int n = t + nn * 128;
        float s = f_b1[n];
        #pragma unroll 4
        for (int k = 0; k < 128; ++k) s += h1_s[k] * f_W1[k * 512 + n];
        f_s[n] = fmaxf(s, 0.f);
    }
    __syncthreads();
    float v = f_b2[t];
    #pragma unroll 4
    for (int k = 0; k < 512; ++k) v += f_s[k] * f_W2[k * 128 + t];
    v += h1_s[t];
    float s = v;
    #pragma unroll
    for (int o = 32; o; o >>= 1) s += __shfl_down(s, o, 64);
    if (lane == 0) red_s[wid] = s;
    __syncthreads();
    float mean = (red_s[0] + red_s[1]) * (1.f / 128.f);
    float d = v - mean;
    float q2 = d * d;
    #pragma unroll
    for (int o = 32; o; o >>= 1) q2 += __shfl_down(q2, o, 64);
    if (lane == 0) red_s[2 + wid] = q2;
    __syncthreads();
    float var = (red_s[2] + red_s[3]) * (1.f / 128.f);
    Wf[tok * 128 + t] = d * rsqrtf(var + 1e-5f) * ln2_g[t] + ln2_b[t];
}

// decode: 16 lanes per triple; U2 bf16 rows (16B/lane), Wf/V fp32
__global__ void __launch_bounds__(256) decode_kernel(
    const int* __restrict__ idx_i, const int* __restrict__ idx_j, const int* __restrict__ idx_k,
    const unsigned short* __restrict__ U2, const float* __restrict__ Wf, const float* __restrict__ V,
    const float* __restrict__ bias, float* __restrict__ out, int n)
{
    const int g = threadIdx.x >> 4;      // 0..15
    const int hl = threadIdx.x & 15;
    int t = blockIdx.x * 16 + g;
    if (t >= n) return;
    int i = idx_i[t], j = idx_j[t], kk = idx_k[t];
    const unsigned short* up = U2 + (long)i * 128 + hl * 8;
    const float* wp = Wf + kk * 128 + hl * 8;
    const float* vp = V + j * 128 + hl * 8;
    uint4 ur = *(const uint4*)up;                 // 8 bf16
    const unsigned short* uu = (const unsigned short*)&ur;
    float4 w0 = *(const float4*)wp,  w1 = *(const float4*)(wp + 4);
    float4 v0 = *(const float4*)vp,  v1 = *(const float4*)(vp + 4);
    float s = b2f(uu[0]) * w0.x * v0.x + b2f(uu[1]) * w0.y * v0.y
            + b2f(uu[2]) * w0.z * v0.z + b2f(uu[3]) * w0.w * v0.w
            + b2f(uu[4]) * w1.x * v1.x + b2f(uu[5]) * w1.y * v1.y
            + b2f(uu[6]) * w1.z * v1.z + b2f(uu[7]) * w1.w * v1.w;
    #pragma unroll
    for (int o = 8; o; o >>= 1) s += __shfl_down(s, o, 16);
    if (hl == 0) out[t] = 1.f / (1.f + expf(-(s + bias[0])));
}

// ---------------------------------------------------------------------------
extern "C" void kernel_launch(void* const* d_in, const int* in_sizes, int n_in,
                              void* d_out, int out_size, void* d_ws, size_t ws_size,
                              hipStream_t stream)
{
    const float* edge_x = (const float*)d_in[0];
    const int*   edge_i = (const int*)d_in[1];
    const int*   edge_k = (const int*)d_in[2];
    const int*   idx_i  = (const int*)d_in[3];
    const int*   idx_j  = (const int*)d_in[4];
    const int*   idx_k  = (const int*)d_in[5];
    const float* u0   = (const float*)d_in[6];
    const float* w0   = (const float*)d_in[7];
    const float* ep_W = (const float*)d_in[8];
    const float* ep_b = (const float*)d_in[9];
    const float* uW   = (const float*)d_in[10];
    const float* ub   = (const float*)d_in[11];
    const float* wW   = (const float*)d_in[12];
    const float* wb   = (const float*)d_in[13];
    const float* pos  = (const float*)d_in[14];
    const float* Wq = (const float*)d_in[15];
    const float* Wk = (const float*)d_in[16];
    const float* Wv = (const float*)d_in[17];
    const float* bq = (const float*)d_in[18];
    const float* bk = (const float*)d_in[19];
    const float* bv = (const float*)d_in[20];
    const float* Wo = (const float*)d_in[21];
    const float* bo = (const float*)d_in[22];
    const float* ln1_g = (const float*)d_in[23];
    const float* ln1_b = (const float*)d_in[24];
    const float* f_W1 = (const float*)d_in[25];
    const float* f_b1 = (const float*)d_in[26];
    const float* f_W2 = (const float*)d_in[27];
    const float* f_b2 = (const float*)d_in[28];
    const float* ln2_g = (const float*)d_in[29];
    const float* ln2_b = (const float*)d_in[30];
    const float* Vmat = (const float*)d_in[31];
    const float* bias = (const float*)d_in[32];

    const int E   = in_sizes[1];
    const int NTt = in_sizes[3];
    const int nNodes = in_sizes[6] / D_DIM;

    char* ws = (char*)d_ws;
    size_t off = 0;
    auto alloc = [&](size_t bytes) -> char* {
        char* p = ws + off;
        off = (off + bytes + 255) & ~(size_t)255;
        return p;
    };
    // zero-initialized region first (single memset, ~38.6 MB)
    unsigned* NmatP  = (unsigned*)alloc((size_t)nNodes * 32 * 4);   // packed u8x4
    float*    Xi     = (float*)alloc((size_t)nNodes * 64 * 4);
    float*    Xkseg  = (float*)alloc(128 * 64 * 4);
    unsigned* cntw   = (unsigned*)alloc(512);
    size_t zeroBytes = off;
    // rest (written before read)
    float* cntraw = (float*)alloc((size_t)nNodes * 4);
    float* invcnt = (float*)alloc((size_t)nNodes * 4);
    unsigned short* U0b = (unsigned short*)alloc((size_t)nNodes * 128 * 2);
    unsigned short* U1b = (unsigned short*)alloc((size_t)nNodes * 128 * 2);
    unsigned short* U2b = (unsigned short*)alloc((size_t)nNodes * 128 * 2);
    float* partials = (float*)alloc((size_t)WB_BLOCKS * 16384 * 4);
    unsigned short* Bt0 = (unsigned short*)alloc(128 * 320 * 2);
    unsigned short* Bt1 = (unsigned short*)alloc(128 * 320 * 2);
    float* W1 = (float*)alloc(65536);
    float* W2 = (float*)alloc(65536);
    float* ebx0 = (float*)alloc(512);
    float* ebx1 = (float*)alloc(512);
    float* Xmat  = (float*)alloc(65536);
    float* qm    = (float*)alloc(65536);
    float* km    = (float*)alloc(65536);
    float* vm    = (float*)alloc(65536);
    float* Wfm   = (float*)alloc(65536);

    const unsigned char* Nmat8 = (const unsigned char*)NmatP;

    const float* uWt0 = uW;
    const float* uWb0 = uW + 128 * 128;
    const float* uWt1 = uW + 256 * 128;
    const float* uWb1 = uW + 256 * 128 + 128 * 128;
    const float* wWt0 = wW;
    const float* wWb0 = wW + 128 * 128;
    const float* wWt1 = wW + 256 * 128;
    const float* wWb1 = wW + 256 * 128 + 128 * 128;

    hipMemsetAsync(d_ws, 0, zeroBytes, stream);

    // ---- edge pass (single launch, full atomic concurrency) ----
    int epb = (E + 1023) / 1024;
    edge_pass_kernel<<<1024, 256, 0, stream>>>(edge_x, edge_i, edge_k, Xi, Xkseg,
                                               NmatP, cntw, E, epb);

    // ---- mid: cnt + u0cvt + prep(layer0) fused ----
    int cntB = (nNodes + 3) / 4;
    mid_kernel<<<cntB + 1024 + 161, 256, 0, stream>>>(
        NmatP, cntraw, invcnt, nNodes, cntB,
        u0, U0b, (long)nNodes * 32,
        uWt0, w0, uWb0, ep_W, ep_b, Bt0, ebx0);

    int npb = (nNodes + WB_BLOCKS - 1) / WB_BLOCKS;
    int la_grid = (nNodes + 127) / 128;

    // ---- layer 0 ----
    wmsgB_mfma<<<WB_BLOCKS, 256, 0, stream>>>(U0b, Nmat8, partials, npb, nNodes);
    layerA_mfma<<<la_grid, 256, 0, stream>>>(U0b, Nmat8, Xi, cntraw, invcnt, Bt0, ub, ebx0, U1b, nNodes);
    wfin_gemm_kernel<<<128, 128, 0, stream>>>(partials, Xkseg, cntw, ep_W, ep_b,
                                              w0, wWt0, wWb0, wb, W1);

    // ---- layer 1 ----
    prep_kernel<<<161, 256, 0, stream>>>(uWt1, W1, uWb1, ep_W, ep_b, Bt1, ebx1);
    wmsgB_mfma<<<WB_BLOCKS, 256, 0, stream>>>(U1b, Nmat8, partials, npb, nNodes);
    layerA_mfma<<<la_grid, 256, 0, stream>>>(U1b, Nmat8, Xi, cntraw, invcnt, Bt1, ub + 128, ebx1, U2b, nNodes);
    wfin_gemm_kernel<<<128, 128, 0, stream>>>(partials, Xkseg, cntw, ep_W, ep_b,
                                              W1, wWt1, wWb1, wb + 128, W2);

    // ---- TimeRefine (2 kernels) ----
    qkvf_kernel<<<192, 256, 0, stream>>>(W2, pos, Wq, Wk, Wv, bq, bk, bv, Xmat, qm, km, vm);
    attn_tail_kernel<<<128, 128, 0, stream>>>(qm, km, vm, Wo, bo, Xmat, ln1_g, ln1_b,
                                              f_W1, f_b1, f_W2, f_b2, ln2_g, ln2_b, Wfm);

    // ---- decode ----
    decode_kernel<<<(NTt + 15) / 16, 256, 0, stream>>>(idx_i, idx_j, idx_k, U2b, Wfm, Vmat,
                                                       bias, (float*)d_out, NTt);
}

// Round 4
// 1076.760 us; speedup vs baseline: 1.7310x; 1.0577x over previous
//
#include <hip/hip_runtime.h>
#include <hip/hip_bf16.h>

#define D_DIM 128
#define KT 128
#define JF 64
#define WB_BLOCKS 256

typedef __attribute__((ext_vector_type(8))) short bf16x8;
typedef __attribute__((ext_vector_type(4))) float f32x4;

__device__ inline unsigned short f2b(float f) {
    __hip_bfloat16 h = __float2bfloat16(f);
    return *reinterpret_cast<unsigned short*>(&h);
}
__device__ inline float b2f(unsigned short u) {
    unsigned int x = ((unsigned int)u) << 16;
    return __uint_as_float(x);
}

// packed bf16 global atomic add (gfx950 global_atomic_pk_add_bf16), inline asm
// so it works regardless of builtin availability. Fire-and-forget (no rtn).
__device__ inline void atomPkAddBf16(unsigned short* addr, unsigned packed) {
    asm volatile("global_atomic_pk_add_bf16 %0, %1, off"
                 :: "v"(addr), "v"(packed) : "memory");
}

// prep body (no LDS): Bt[n][kk] bf16, stride 320. Wl==nullptr -> skip the
// W-dependent middle cols (128..255), which wfin_gemm writes later.
__device__ inline void prep_body(int idx, const float* uWt, const float* Wl,
                                 const float* uWb, const float* ep_W,
                                 const float* ep_b, unsigned short* Bt,
                                 float* ebx)
{
    if (idx < 128 * 320) {
        int n = idx / 320, kk = idx - n * 320;
        if (kk < 128) {
            Bt[idx] = f2b(uWt[kk * 128 + n]);
        } else if (kk < 256) {
            if (Wl) {
                const float* a = Wl + (kk - 128) * 128;
                float s = 0.f;
                #pragma unroll 8
                for (int j = 0; j < 128; ++j) s += a[j] * uWb[j * 128 + n];
                Bt[idx] = f2b(s);
            }
        } else {
            const float* a = ep_W + (kk - 256) * 128;
            float s = 0.f;
            #pragma unroll 8
            for (int j = 0; j < 128; ++j) s += a[j] * uWb[j * 128 + n];
            Bt[idx] = f2b(s);
        }
    } else if (idx < 128 * 320 + 128) {
        int n = idx - 128 * 320;
        float s = 0.f;
        #pragma unroll 8
        for (int j = 0; j < 128; ++j) s += ep_b[j] * uWb[j * 128 + n];
        ebx[n] = s;
    }
}

// ---------------------------------------------------------------------------
// edge_fused: blocks [0,1024) edge pass; [1024,2048) u0->bf16 cvt;
// [2048,2209) prep layer0 (full); [2209,2370) prep layer1 (const cols only).
// Edge: half-wave (32 lanes) per edge, float2/lane. Xi accumulated in BF16
// via pk_add atomics (halves the dominant atomic write traffic 256->128 MB).
// Xk/cntw LDS-privatized; Nmat packed u8x4-in-u32 atomics.
// ---------------------------------------------------------------------------
__global__ void __launch_bounds__(256) edge_fused_kernel(
    const float* __restrict__ edge_x, const int* __restrict__ edge_i,
    const int* __restrict__ edge_k, unsigned short* __restrict__ XiB,
    float* __restrict__ Xk, unsigned* __restrict__ NmatP,
    unsigned* __restrict__ cntw, int E, int epb,
    const float* __restrict__ u0, unsigned short* __restrict__ U0b, long n4,
    const float* __restrict__ uWt0, const float* __restrict__ w0,
    const float* __restrict__ uWb0, const float* __restrict__ uWt1,
    const float* __restrict__ uWb1, const float* __restrict__ ep_W,
    const float* __restrict__ ep_b,
    unsigned short* __restrict__ Bt0, float* __restrict__ ebx0,
    unsigned short* __restrict__ Bt1, float* __restrict__ ebx1)
{
    __shared__ float xk_s[KT * JF];      // 32 KB
    __shared__ unsigned cw_s[KT];
    const unsigned bid = blockIdx.x;
    if (bid < 1024) {
        for (int t = threadIdx.x; t < KT * JF; t += 256) xk_s[t] = 0.f;
        if (threadIdx.x < KT) cw_s[threadIdx.x] = 0u;
        __syncthreads();
        const int wid = threadIdx.x >> 6, lane = threadIdx.x & 63;
        const int half = lane >> 5, l2 = lane & 31;
        const long base = (long)bid * epb;
        for (int c = wid * 2 + half; c < epb; c += 8) {
            long e = base + c;
            if (e >= (long)E) break;
            int i = edge_i[e], k = edge_k[e];
            float2 x2 = *(const float2*)&edge_x[e * 64 + l2 * 2];
            unsigned pk = ((unsigned)f2b(x2.y) << 16) | (unsigned)f2b(x2.x);
            atomPkAddBf16(&XiB[(long)i * 64 + l2 * 2], pk);
            unsafeAtomicAdd(&xk_s[k * 64 + l2 * 2], x2.x);
            unsafeAtomicAdd(&xk_s[k * 64 + l2 * 2 + 1], x2.y);
            if (l2 == 0) atomicAdd(&NmatP[(long)i * 32 + (k >> 2)], 1u << ((k & 3) * 8));
            if (l2 == 1) atomicAdd(&cw_s[k], 1u);
        }
        asm volatile("s_waitcnt vmcnt(0)" ::: "memory");
        __syncthreads();
        for (int t = threadIdx.x; t < KT * JF; t += 256) {
            float v = xk_s[t];
            if (v != 0.f) unsafeAtomicAdd(&Xk[t], v);
        }
        if (threadIdx.x < KT && cw_s[threadIdx.x]) atomicAdd(&cntw[threadIdx.x], cw_s[threadIdx.x]);
    } else if (bid < 2048) {
        long i = (long)(bid - 1024) * 256 + threadIdx.x;
        long stride = (long)1024 * 256;
        for (; i < n4; i += stride) {
            float4 v = *(const float4*)&u0[i * 4];
            ushort4 o = make_ushort4(f2b(v.x), f2b(v.y), f2b(v.z), f2b(v.w));
            *(ushort4*)&U0b[i * 4] = o;
        }
    } else if (bid < 2209) {
        prep_body((int)(bid - 2048) * 256 + threadIdx.x, uWt0, w0, uWb0, ep_W, ep_b, Bt0, ebx0);
    } else {
        prep_body((int)(bid - 2209) * 256 + threadIdx.x, uWt1, nullptr, uWb1, ep_W, ep_b, Bt1, ebx1);
    }
}

// cnt: per-node edge count from packed u8 NmatP
__global__ void __launch_bounds__(256) cnt_kernel(
    const unsigned* __restrict__ NmatP, float* __restrict__ cntraw,
    float* __restrict__ invcnt, int nNodes)
{
    int row = blockIdx.x * 4 + (threadIdx.x >> 6);
    int lane = threadIdx.x & 63;
    if (row >= nNodes || lane >= 32) return;
    unsigned wv = NmatP[(long)row * 32 + lane];
    unsigned s = (wv & 0xFF) + ((wv >> 8) & 0xFF) + ((wv >> 16) & 0xFF) + (wv >> 24);
    #pragma unroll
    for (int o = 16; o; o >>= 1) s += __shfl_down(s, o, 32);
    if (lane == 0) {
        float c = (float)s;
        cntraw[row] = c;
        invcnt[row] = 1.f / fmaxf(c, 1.f);
    }
}

// ---------------------------------------------------------------------------
// dual_mfma: blocks [0,wbB) = wmsgB (partial[b] = N^T_chunk @ U_chunk);
// blocks [wbB,..) = layerA (U_out = relu([U|N*inv|Xi*inv] @ Bt + ub + f*ebx)).
// Independent outputs -> safe to co-schedule; overlap hides each other's
// latency phases (both are low-occupancy when launched alone).
// ---------------------------------------------------------------------------
__global__ void __launch_bounds__(256) dual_mfma(
    const unsigned short* __restrict__ U_in, const unsigned char* __restrict__ Nmat8,
    float* __restrict__ partial, int nodes_per_block,
    const unsigned short* __restrict__ XiB, const float* __restrict__ cntraw,
    const float* __restrict__ invcnt, const unsigned short* __restrict__ Bt,
    const float* __restrict__ ub_l, const float* __restrict__ ebx,
    unsigned short* __restrict__ U_out, int nNodes, int wbB)
{
    __shared__ __align__(16) unsigned short A_s[128][40];
    __shared__ __align__(16) unsigned short B_s[128][40];
    const int tid = threadIdx.x;
    const int w = tid >> 6, lane = tid & 63;
    const int quad = lane >> 4, l16 = lane & 15;
    f32x4 acc[2][8];
    #pragma unroll
    for (int a = 0; a < 2; ++a)
        #pragma unroll
        for (int b = 0; b < 8; ++b) acc[a][b] = (f32x4){0.f, 0.f, 0.f, 0.f};

    if ((int)blockIdx.x < wbB) {
        // ---------------- wmsgB ----------------
        int base = blockIdx.x * nodes_per_block;
        int end = min(base + nodes_per_block, nNodes);
        const int nn = tid >> 3;          // 0..31
        const int cc = (tid & 7) * 16;    // 0..112
        for (int g = base; g < end; g += 32) {
            int cnt = min(32, end - g);
            __syncthreads();
            if (nn < cnt) {
                int node = g + nn;
                uint4 nb = *(const uint4*)&Nmat8[(long)node * 128 + cc];
                const unsigned char* nbp = (const unsigned char*)&nb;
                uint4 ua = *(const uint4*)&U_in[(long)node * 128 + cc];
                uint4 ubb = *(const uint4*)&U_in[(long)node * 128 + cc + 8];
                unsigned short uv[16];
                *(uint4*)&uv[0] = ua;
                *(uint4*)&uv[8] = ubb;
                #pragma unroll
                for (int j = 0; j < 16; ++j) {
                    A_s[cc + j][nn] = f2b((float)nbp[j]);
                    B_s[cc + j][nn] = uv[j];
                }
            } else {
                #pragma unroll
                for (int j = 0; j < 16; ++j) { A_s[cc + j][nn] = 0; B_s[cc + j][nn] = 0; }
            }
            __syncthreads();
            bf16x8 a0 = *(const bf16x8*)&A_s[w * 32 + l16][quad * 8];
            bf16x8 a1 = *(const bf16x8*)&A_s[w * 32 + 16 + l16][quad * 8];
            #pragma unroll
            for (int nt = 0; nt < 8; ++nt) {
                bf16x8 b = *(const bf16x8*)&B_s[nt * 16 + l16][quad * 8];
                acc[0][nt] = __builtin_amdgcn_mfma_f32_16x16x32_bf16(a0, b, acc[0][nt], 0, 0, 0);
                acc[1][nt] = __builtin_amdgcn_mfma_f32_16x16x32_bf16(a1, b, acc[1][nt], 0, 0, 0);
            }
        }
        float* my = partial + (size_t)blockIdx.x * 16384;
        #pragma unroll
        for (int mt = 0; mt < 2; ++mt)
            #pragma unroll
            for (int r = 0; r < 4; ++r) {
                int row = w * 32 + mt * 16 + quad * 4 + r;
                #pragma unroll
                for (int nt = 0; nt < 8; ++nt)
                    my[row * 128 + nt * 16 + l16] = acc[mt][nt][r];
            }
    } else {
        // ---------------- layerA ----------------
        const int nodeBase = ((int)blockIdx.x - wbB) * 128;
        const int rr = tid >> 3;          // 0..31
        const int kc = (tid & 7) * 4;     // 0..28
        for (int ks = 0; ks < 10; ++ks) {
            const int k0 = ks * 32;
            __syncthreads();
            {
                int n = tid & 127, seg = tid >> 7;
                const unsigned short* src = Bt + n * 320 + k0 + seg * 16;
                uint4 p0 = *(const uint4*)(src);
                uint4 p1 = *(const uint4*)(src + 8);
                *(uint4*)&B_s[n][seg * 16]     = p0;
                *(uint4*)&B_s[n][seg * 16 + 8] = p1;
            }
            #pragma unroll
            for (int p = 0; p < 4; ++p) {
                int r = p * 32 + rr;
                int node = nodeBase + r;
                ushort4 w4 = make_ushort4(0, 0, 0, 0);
                if (node < nNodes) {
                    if (ks < 4) {
                        w4 = *(const ushort4*)&U_in[(long)node * 128 + k0 + kc];
                    } else if (ks < 8) {
                        float inv = invcnt[node];
                        const unsigned char* np_ = &Nmat8[(long)node * 128 + (k0 - 128) + kc];
                        w4 = make_ushort4(f2b((float)np_[0] * inv), f2b((float)np_[1] * inv),
                                          f2b((float)np_[2] * inv), f2b((float)np_[3] * inv));
                    } else {
                        float inv = invcnt[node];
                        ushort4 x = *(const ushort4*)&XiB[(long)node * 64 + (k0 - 256) + kc];
                        w4 = make_ushort4(f2b(b2f(x.x) * inv), f2b(b2f(x.y) * inv),
                                          f2b(b2f(x.z) * inv), f2b(b2f(x.w) * inv));
                    }
                }
                *(ushort4*)&A_s[r][kc] = w4;
            }
            __syncthreads();
            bf16x8 a0 = *(const bf16x8*)&A_s[w * 32 + l16][quad * 8];
            bf16x8 a1 = *(const bf16x8*)&A_s[w * 32 + 16 + l16][quad * 8];
            #pragma unroll
            for (int nt = 0; nt < 8; ++nt) {
                bf16x8 b = *(const bf16x8*)&B_s[nt * 16 + l16][quad * 8];
                acc[0][nt] = __builtin_amdgcn_mfma_f32_16x16x32_bf16(a0, b, acc[0][nt], 0, 0, 0);
                acc[1][nt] = __builtin_amdgcn_mfma_f32_16x16x32_bf16(a1, b, acc[1][nt], 0, 0, 0);
            }
        }
        #pragma unroll
        for (int mt = 0; mt < 2; ++mt) {
            #pragma unroll
            for (int r = 0; r < 4; ++r) {
                int row = w * 32 + mt * 16 + quad * 4 + r;
                int node = nodeBase + row;
                if (node < nNodes) {
                    float flag = (cntraw[node] > 0.f) ? 1.f : 0.f;
                    #pragma unroll
                    for (int nt = 0; nt < 8; ++nt) {
                        int col = nt * 16 + l16;
                        float vv = acc[mt][nt][r] + ub_l[col] + flag * ebx[col];
                        U_out[(long)node * 128 + col] = f2b(fmaxf(vv, 0.f));
                    }
                }
            }
        }
    }
}

// fused partial-reduce + wmsg_fin + W-layer GEMM (+ next layer's Bt middle
// cols: block kk owns W_out row kk, so it can emit Bt_next[:,128+kk]).
__global__ void __launch_bounds__(128) wfin_gemm_kernel(
    const float* __restrict__ partial, const float* __restrict__ Xk,
    const unsigned* __restrict__ cntw, const float* __restrict__ ep_W,
    const float* __restrict__ ep_b, const float* __restrict__ Wrow,
    const float* __restrict__ wWt, const float* __restrict__ wWb,
    const float* __restrict__ wb_l, float* __restrict__ Wout,
    const float* __restrict__ uWb_next, unsigned short* __restrict__ Bt_next)
{
    __shared__ float msg_s[128];
    __shared__ float a_s[128];
    __shared__ float w_s[128];
    const int kk = blockIdx.x, t = threadIdx.x;
    float c = (float)cntw[kk];
    {
        float s = 0.f;
        const float* pp = partial + kk * 128 + t;
        #pragma unroll 8
        for (int b = 0; b < WB_BLOCKS; ++b) s += pp[(size_t)b * 16384];
        const float* xk = Xk + kk * 64;
        #pragma unroll 8
        for (int j = 0; j < 64; ++j) s += xk[j] * ep_W[j * 128 + t];
        s += c * ep_b[t];
        msg_s[t] = s / fmaxf(c, 1.f);
        a_s[t] = Wrow[kk * 128 + t];
    }
    __syncthreads();
    float s = wb_l[t];
    #pragma unroll 4
    for (int k = 0; k < 128; ++k) s += a_s[k] * wWt[k * 128 + t];
    #pragma unroll 4
    for (int k = 0; k < 128; ++k) s += msg_s[k] * wWb[k * 128 + t];
    float wv = fmaxf(s, 0.f);
    Wout[kk * 128 + t] = wv;
    if (Bt_next) {
        w_s[t] = wv;
        __syncthreads();
        float bt = 0.f;
        #pragma unroll 4
        for (int j = 0; j < 128; ++j) bt += w_s[j] * uWb_next[j * 128 + t];
        Bt_next[t * 320 + 128 + kk] = f2b(bt);
    }
}

// fused (W2+pos) + Q/K/V projection: 128 tokens x 384 outputs
__global__ void qkvf_kernel(const float* __restrict__ W2, const float* __restrict__ pos,
                            const float* __restrict__ Wq, const float* __restrict__ Wk,
                            const float* __restrict__ Wv, const float* __restrict__ bq,
                            const float* __restrict__ bk, const float* __restrict__ bv,
                            float* __restrict__ Xmat,
                            float* __restrict__ qm, float* __restrict__ km, float* __restrict__ vm)
{
    int idx = blockIdx.x * 256 + threadIdx.x;
    if (idx >= 128 * 384) return;
    int m = idx / 384, c = idx - m * 384;
    int sel = c >> 7, n = c & 127;
    const float* W = (sel == 0) ? Wq : (sel == 1) ? Wk : Wv;
    const float* b = (sel == 0) ? bq : (sel == 1) ? bk : bv;
    float s = b[n];
    const float* x2 = W2 + m * 128;
    const float* xp = pos + m * 128;
    #pragma unroll 8
    for (int k = 0; k < 128; ++k) s += (x2[k] + xp[k]) * W[k * 128 + n];
    float* o = (sel == 0) ? qm : (sel == 1) ? km : vm;
    o[m * 128 + n] = s;
    if (sel == 0) Xmat[m * 128 + n] = x2[n] + xp[n];
}

// fused attention + out-proj + LN1 + FFN + LN2: one block (128 thr) per token
__global__ void __launch_bounds__(128) attn_tail_kernel(
    const float* __restrict__ q, const float* __restrict__ kmat,
    const float* __restrict__ vmat, const float* __restrict__ Wo,
    const float* __restrict__ bo, const float* __restrict__ Xmat,
    const float* __restrict__ ln1_g, const float* __restrict__ ln1_b,
    const float* __restrict__ f_W1, const float* __restrict__ f_b1,
    const float* __restrict__ f_W2, const float* __restrict__ f_b2,
    const float* __restrict__ ln2_g, const float* __restrict__ ln2_b,
    float* __restrict__ Wf)
{
    __shared__ float p_s[128];
    __shared__ float a_s[128];
    __shared__ float h1_s[128];
    __shared__ float f_s[512];
    __shared__ float red_s[4];
    const int tok = blockIdx.x;
    const int t = threadIdx.x;
    const int lane = t & 63, wid = t >> 6;
    for (int h = 0; h < 2; ++h) {
        const float* qr = q + tok * 128 + h * 64;
        const float* kr = kmat + t * 128 + h * 64;
        float s = 0.f;
        #pragma unroll
        for (int d = 0; d < 64; ++d) s += qr[d] * kr[d];
        s *= 0.125f;
        float m = s;
        #pragma unroll
        for (int o = 32; o; o >>= 1) m = fmaxf(m, __shfl_down(m, o, 64));
        if (lane == 0) red_s[wid] = m;
        __syncthreads();
        m = fmaxf(red_s[0], red_s[1]);
        float ev = expf(s - m);
        float ss = ev;
        #pragma unroll
        for (int o = 32; o; o >>= 1) ss += __shfl_down(ss, o, 64);
        if (lane == 0) red_s[2 + wid] = ss;
        __syncthreads();
        float tot = red_s[2] + red_s[3];
        p_s[t] = ev / tot;
        __syncthreads();
        if (t < 64) {
            float o = 0.f;
            #pragma unroll 8
            for (int j = 0; j < 128; ++j) o += p_s[j] * vmat[j * 128 + h * 64 + t];
            a_s[h * 64 + t] = o;
        }
        __syncthreads();
    }
    {
        float v = bo[t];
        #pragma unroll 4
        for (int k = 0; k < 128; ++k) v += a_s[k] * Wo[k * 128 + t];
        v += Xmat[tok * 128 + t];
        float s = v;
        #pragma unroll
        for (int o = 32; o; o >>= 1) s += __shfl_down(s, o, 64);
        if (lane == 0) red_s[wid] = s;
        __syncthreads();
        float mean = (red_s[0] + red_s[1]) * (1.f / 128.f);
        float d = v - mean;
        float q2 = d * d;
        #pragma unroll
        for (int o = 32; o; o >>= 1) q2 += __shfl_down(q2, o, 64);
        if (lane == 0) red_s[2 + wid] = q2;
        __syncthreads();
        float var = (red_s[2] + red_s[3]) * (1.f / 128.f);
        h1_s[t] = d * rsqrtf(var + 1e-5f) * ln1_g[t] + ln1_b[t];
        __syncthreads();
    }
    #pragma unroll
    for (int nn = 0; nn < 4; ++nn) {
        int n = t + nn * 128;
        float s = f_b1[n];
        #pragma unroll 4
        for (int k = 0; k < 128; ++k) s += h1_s[k] * f_W1[k * 512 + n];
        f_s[n] = fmaxf(s, 0.f);
    }
    __syncthreads();
    float v = f_b2[t];
    #pragma unroll 4
    for (int k = 0; k < 512; ++k) v += f_s[k] * f_W2[k * 128 + t];
    v += h1_s[t];
    float s = v;
    #pragma unroll
    for (int o = 32; o; o >>= 1) s += __shfl_down(s, o, 64);
    if (lane == 0) red_s[wid] = s;
    __syncthreads();
    float mean = (red_s[0] + red_s[1]) * (1.f / 128.f);
    float d = v - mean;
    float q2 = d * d;
    #pragma unroll
    for (int o = 32; o; o >>= 1) q2 += __shfl_down(q2, o, 64);
    if (lane == 0) red_s[2 + wid] = q2;
    __syncthreads();
    float var = (red_s[2] + red_s[3]) * (1.f / 128.f);
    Wf[tok * 128 + t] = d * rsqrtf(var + 1e-5f) * ln2_g[t] + ln2_b[t];
}

// decode: 16 lanes per triple; U2 bf16 rows (16B/lane), Wf/V fp32
__global__ void __launch_bounds__(256) decode_kernel(
    const int* __restrict__ idx_i, const int* __restrict__ idx_j, const int* __restrict__ idx_k,
    const unsigned short* __restrict__ U2, const float* __restrict__ Wf, const float* __restrict__ V,
    const float* __restrict__ bias, float* __restrict__ out, int n)
{
    const int g = threadIdx.x >> 4;      // 0..15
    const int hl = threadIdx.x & 15;
    int t = blockIdx.x * 16 + g;
    if (t >= n) return;
    int i = idx_i[t], j = idx_j[t], kk = idx_k[t];
    const unsigned short* up = U2 + (long)i * 128 + hl * 8;
    const float* wp = Wf + kk * 128 + hl * 8;
    const float* vp = V + j * 128 + hl * 8;
    uint4 ur = *(const uint4*)up;                 // 8 bf16
    const unsigned short* uu = (const unsigned short*)&ur;
    float4 w0 = *(const float4*)wp,  w1 = *(const float4*)(wp + 4);
    float4 v0 = *(const float4*)vp,  v1 = *(const float4*)(vp + 4);
    float s = b2f(uu[0]) * w0.x * v0.x + b2f(uu[1]) * w0.y * v0.y
            + b2f(uu[2]) * w0.z * v0.z + b2f(uu[3]) * w0.w * v0.w
            + b2f(uu[4]) * w1.x * v1.x + b2f(uu[5]) * w1.y * v1.y
            + b2f(uu[6]) * w1.z * v1.z + b2f(uu[7]) * w1.w * v1.w;
    #pragma unroll
    for (int o = 8; o; o >>= 1) s += __shfl_down(s, o, 16);
    if (hl == 0) out[t] = 1.f / (1.f + expf(-(s + bias[0])));
}

// ---------------------------------------------------------------------------
extern "C" void kernel_launch(void* const* d_in, const int* in_sizes, int n_in,
                              void* d_out, int out_size, void* d_ws, size_t ws_size,
                              hipStream_t stream)
{
    const float* edge_x = (const float*)d_in[0];
    const int*   edge_i = (const int*)d_in[1];
    const int*   edge_k = (const int*)d_in[2];
    const int*   idx_i  = (const int*)d_in[3];
    const int*   idx_j  = (const int*)d_in[4];
    const int*   idx_k  = (const int*)d_in[5];
    const float* u0   = (const float*)d_in[6];
    const float* w0   = (const float*)d_in[7];
    const float* ep_W = (const float*)d_in[8];
    const float* ep_b = (const float*)d_in[9];
    const float* uW   = (const float*)d_in[10];
    const float* ub   = (const float*)d_in[11];
    const float* wW   = (const float*)d_in[12];
    const float* wb   = (const float*)d_in[13];
    const float* pos  = (const float*)d_in[14];
    const float* Wq = (const float*)d_in[15];
    const float* Wk = (const float*)d_in[16];
    const float* Wv = (const float*)d_in[17];
    const float* bq = (const float*)d_in[18];
    const float* bk = (const float*)d_in[19];
    const float* bv = (const float*)d_in[20];
    const float* Wo = (const float*)d_in[21];
    const float* bo = (const float*)d_in[22];
    const float* ln1_g = (const float*)d_in[23];
    const float* ln1_b = (const float*)d_in[24];
    const float* f_W1 = (const float*)d_in[25];
    const float* f_b1 = (const float*)d_in[26];
    const float* f_W2 = (const float*)d_in[27];
    const float* f_b2 = (const float*)d_in[28];
    const float* ln2_g = (const float*)d_in[29];
    const float* ln2_b = (const float*)d_in[30];
    const float* Vmat = (const float*)d_in[31];
    const float* bias = (const float*)d_in[32];

    const int E   = in_sizes[1];
    const int NTt = in_sizes[3];
    const int nNodes = in_sizes[6] / D_DIM;

    char* ws = (char*)d_ws;
    size_t off = 0;
    auto alloc = [&](size_t bytes) -> char* {
        char* p = ws + off;
        off = (off + bytes + 255) & ~(size_t)255;
        return p;
    };
    // zero-initialized region first (single memset, ~25.7 MB)
    unsigned* NmatP  = (unsigned*)alloc((size_t)nNodes * 32 * 4);          // packed u8x4
    unsigned short* XiB = (unsigned short*)alloc((size_t)nNodes * 64 * 2); // bf16 Xi
    float*    Xkseg  = (float*)alloc(128 * 64 * 4);
    unsigned* cntw   = (unsigned*)alloc(512);
    size_t zeroBytes = off;
    // rest (written before read)
    float* cntraw = (float*)alloc((size_t)nNodes * 4);
    float* invcnt = (float*)alloc((size_t)nNodes * 4);
    unsigned short* U0b = (unsigned short*)alloc((size_t)nNodes * 128 * 2);
    unsigned short* U1b = (unsigned short*)alloc((size_t)nNodes * 128 * 2);
    unsigned short* U2b = (unsigned short*)alloc((size_t)nNodes * 128 * 2);
    float* partials = (float*)alloc((size_t)WB_BLOCKS * 16384 * 4);
    unsigned short* Bt0 = (unsigned short*)alloc(128 * 320 * 2);
    unsigned short* Bt1 = (unsigned short*)alloc(128 * 320 * 2);
    float* W1 = (float*)alloc(65536);
    float* W2 = (float*)alloc(65536);
    float* ebx0 = (float*)alloc(512);
    float* ebx1 = (float*)alloc(512);
    float* Xmat  = (float*)alloc(65536);
    float* qm    = (float*)alloc(65536);
    float* km    = (float*)alloc(65536);
    float* vm    = (float*)alloc(65536);
    float* Wfm   = (float*)alloc(65536);

    const unsigned char* Nmat8 = (const unsigned char*)NmatP;

    const float* uWt0 = uW;
    const float* uWb0 = uW + 128 * 128;
    const float* uWt1 = uW + 256 * 128;
    const float* uWb1 = uW + 256 * 128 + 128 * 128;
    const float* wWt0 = wW;
    const float* wWb0 = wW + 128 * 128;
    const float* wWt1 = wW + 256 * 128;
    const float* wWb1 = wW + 256 * 128 + 128 * 128;

    hipMemsetAsync(d_ws, 0, zeroBytes, stream);

    // ---- edge + u0cvt + prep0(full) + prep1(const cols) in one launch ----
    int epb = (E + 1023) / 1024;
    edge_fused_kernel<<<2370, 256, 0, stream>>>(
        edge_x, edge_i, edge_k, XiB, Xkseg, NmatP, cntw, E, epb,
        u0, U0b, (long)nNodes * 32,
        uWt0, w0, uWb0, uWt1, uWb1, ep_W, ep_b, Bt0, ebx0, Bt1, ebx1);

    cnt_kernel<<<(nNodes + 3) / 4, 256, 0, stream>>>(NmatP, cntraw, invcnt, nNodes);

    int npb = (nNodes + WB_BLOCKS - 1) / WB_BLOCKS;
    int la_grid = (nNodes + 127) / 128;

    // ---- layer 0: wmsgB || layerA, then wfin (+Bt1 middle cols) ----
    dual_mfma<<<WB_BLOCKS + la_grid, 256, 0, stream>>>(
        U0b, Nmat8, partials, npb, XiB, cntraw, invcnt, Bt0, ub, ebx0, U1b, nNodes, WB_BLOCKS);
    wfin_gemm_kernel<<<128, 128, 0, stream>>>(partials, Xkseg, cntw, ep_W, ep_b,
                                              w0, wWt0, wWb0, wb, W1, uWb1, Bt1);

    // ---- layer 1 ----
    dual_mfma<<<WB_BLOCKS + la_grid, 256, 0, stream>>>(
        U1b, Nmat8, partials, npb, XiB, cntraw, invcnt, Bt1, ub + 128, ebx1, U2b, nNodes, WB_BLOCKS);
    wfin_gemm_kernel<<<128, 128, 0, stream>>>(partials, Xkseg, cntw, ep_W, ep_b,
                                              W1, wWt1, wWb1, wb + 128, W2, nullptr, nullptr);

    // ---- TimeRefine ----
    qkvf_kernel<<<192, 256, 0, stream>>>(W2, pos, Wq, Wk, Wv, bq, bk, bv, Xmat, qm, km, vm);
    attn_tail_kernel<<<128, 128, 0, stream>>>(qm, km, vm, Wo, bo, Xmat, ln1_g, ln1_b,
                                              f_W1, f_b1, f_W2, f_b2, ln2_g, ln2_b, Wfm);

    // ---- decode ----
    decode_kernel<<<(NTt + 15) / 16, 256, 0, stream>>>(idx_i, idx_j, idx_k, U2b, Wfm, Vmat,
                                                       bias, (float*)d_out, NTt);
}